// Round 2
// baseline (592.066 us; speedup 1.0000x reference)
//
#include <hip/hip_runtime.h>

typedef __bf16 bf16_t;
typedef bf16_t bf16x4 __attribute__((ext_vector_type(4)));
typedef bf16_t bf16x8 __attribute__((ext_vector_type(8)));
typedef float f32x4 __attribute__((ext_vector_type(4)));

#define DD 1024
#define TT 4096

__device__ __forceinline__ void gload16(const void* g, void* l) {
    __builtin_amdgcn_global_load_lds(
        (const __attribute__((address_space(1))) void*)g,
        (__attribute__((address_space(3))) void*)l, 16, 0, 0);
}

// ---------------- fp32 -> bf16 convert ----------------
__global__ __launch_bounds__(256) void cvt_bf16_k(const float* __restrict__ s,
                                                  bf16_t* __restrict__ d, int n) {
    int i = (blockIdx.x * 256 + threadIdx.x) * 4;
    if (i < n) {
        const float4 v = *(const float4*)(s + i);
        bf16x4 o;
        o[0] = (bf16_t)v.x; o[1] = (bf16_t)v.y; o[2] = (bf16_t)v.z; o[3] = (bf16_t)v.w;
        *(bf16x4*)(d + i) = o;
    }
}

// ---------------- interleaved convert: dst row 2c = s0 row c, 2c+1 = s1 row c ----------------
__global__ __launch_bounds__(256) void cvt_ileave_k(const float* __restrict__ s0,
                                                    const float* __restrict__ s1,
                                                    bf16_t* __restrict__ d, int total) {
    int i = (blockIdx.x * 256 + threadIdx.x) * 4;
    if (i < total) {
        const int rp = i >> 10, k = i & 1023;
        const int c = rp >> 1;
        const float* src = ((rp & 1) ? s1 : s0) + (long)c * 1024 + k;
        const float4 v = *(const float4*)src;
        bf16x4 o;
        o[0] = (bf16_t)v.x; o[1] = (bf16_t)v.y; o[2] = (bf16_t)v.z; o[3] = (bf16_t)v.w;
        *(bf16x4*)(d + i) = o;
    }
}

// ---------------- rmsnorm (1 block per row, 256 thr x 4 elems), bf16 out ----------------
__global__ __launch_bounds__(256) void rmsnorm_k(const float* __restrict__ x,
                                                 const float* __restrict__ w,
                                                 bf16_t* __restrict__ ob) {
    const long row = blockIdx.x;
    const float* xr = x + row * DD;
    const int t4 = threadIdx.x * 4;
    float4 v = *(const float4*)(xr + t4);
    float s = v.x*v.x + v.y*v.y + v.z*v.z + v.w*v.w;
    #pragma unroll
    for (int off = 1; off < 64; off <<= 1) s += __shfl_xor(s, off);
    __shared__ float red[4];
    if ((threadIdx.x & 63) == 0) red[threadIdx.x >> 6] = s;
    __syncthreads();
    float tot = red[0] + red[1] + red[2] + red[3];
    float sc = rsqrtf(tot * (1.0f / DD) + 1e-6f);
    float4 wv = *(const float4*)(w + t4);
    bf16x4 o;
    o[0] = (bf16_t)(v.x*sc*wv.x); o[1] = (bf16_t)(v.y*sc*wv.y);
    o[2] = (bf16_t)(v.z*sc*wv.z); o[3] = (bf16_t)(v.w*sc*wv.w);
    *(bf16x4*)(ob + row * DD + t4) = o;
}

// ---------------- causal depthwise conv K=4 (bf16 in, bf16 out) ----------------
__global__ __launch_bounds__(256) void conv_k(const bf16_t* __restrict__ h,
                                              const float* __restrict__ cw,
                                              const float* __restrict__ cb,
                                              bf16_t* __restrict__ hc) {
    const long idx = (long)blockIdx.x * 256 + threadIdx.x;  // over B*T*D
    const int d = (int)(idx & (DD - 1));
    const long bt = idx >> 10;
    const int t = (int)(bt & (TT - 1));
    const float w0 = cw[d*4+0], w1 = cw[d*4+1], w2 = cw[d*4+2], w3 = cw[d*4+3];
    const bf16_t* hp = h + bt * DD + d;
    float acc = cb[d] + (float)hp[0] * w3;
    if (t >= 1) acc += (float)hp[-DD]     * w2;
    if (t >= 2) acc += (float)hp[-2*DD]   * w1;
    if (t >= 3) acc += (float)hp[-3*DD]   * w0;
    hc[idx] = (bf16_t)acc;
}

// ---------------- chunked scan pass1: in-place (a,s) -> (cum_decay, intra) ----------------
__global__ __launch_bounds__(256) void scan1_k(float* __restrict__ ap,
                                               float* __restrict__ sp,
                                               float* __restrict__ cd63,
                                               float* __restrict__ i63) {
    const int d = blockIdx.x * 256 + threadIdx.x;  // 0..1023
    const int c = blockIdx.y;                      // chunk 0..63
    const int b = blockIdx.z;                      // batch
    const long rowbase = (long)b * TT + (long)c * 64;
    float la = 0.0f, rs = 0.0f, cdv = 0.0f, it = 0.0f;
    for (int t = 0; t < 64; t++) {
        const long off = (rowbase + t) * DD + d;
        const float a = ap[off];
        const float s = sp[off];
        const float sig = sqrtf(fmaxf(1.0f - a * a, 1e-8f)) * s;
        la += __logf(fmaxf(a, 1e-10f));
        cdv = __expf(la);
        rs += sig / fmaxf(cdv, 1e-10f);
        it = cdv * rs;
        ap[off] = cdv;
        sp[off] = it;
    }
    const long o = ((long)b * 64 + c) * DD + d;
    cd63[o] = cdv;
    i63[o]  = it;
}

// ---------------- pass2: cross-chunk carry (state ENTERING each chunk) ----------------
__global__ __launch_bounds__(256) void scan2_k(const float* __restrict__ cd63,
                                               const float* __restrict__ i63,
                                               float* __restrict__ carry_in) {
    const int g = blockIdx.x * 256 + threadIdx.x;  // 0..2047
    const int b = g >> 10, d = g & (DD - 1);
    float st = 0.0f;
    for (int c = 0; c < 64; c++) {
        const long o = ((long)b * 64 + c) * DD + d;
        carry_in[o] = st;
        st = i63[o] + cd63[o] * st;
    }
}

// ---------------- pass3: rec = bf16(intra + cd * carry_in) ----------------
__global__ __launch_bounds__(256) void scan3_k(const float* __restrict__ cd,
                                               const float* __restrict__ intra,
                                               const float* __restrict__ carry_in,
                                               bf16_t* __restrict__ rec) {
    const long idx = (long)blockIdx.x * 256 + threadIdx.x;  // B*T*D
    const int d = (int)(idx & (DD - 1));
    const long row = idx >> 10;
    const long b = row >> 12;
    const int t = (int)(row & (TT - 1));
    const int c = t >> 6;
    const float st = carry_in[((b * 64) + c) * DD + d];
    rec[idx] = (bf16_t)(intra[idx] + cd[idx] * st);
}

// ---------------- bf16 GEMM, C = A(M,K) * B(N,K)^T, m97 structure ----------------
// EPI 0: a-plane:  outF[r*ldc+c] = sigmoid(acc + aux[c])
// EPI 1: addres:   outF[r*ldc+c] = acc + aux[r*ldc+c]    (aux may alias outF)
// EPI 2: iv pair:  even lane writes outF[r*ldc+(c>>1)] = sigmoid(acc_i)*acc_v
// EPI 3: gu pair:  even lane writes outB[r*ldc+(c>>1)] = silu(acc_g)*acc_u
enum { EPI_SIGB = 0, EPI_ADDRES = 1, EPI_IV = 2, EPI_GU = 3 };

template<int EPI>
__global__ __launch_bounds__(256) void gemm_k(const bf16_t* __restrict__ A,
                                              const bf16_t* __restrict__ B,
                                              int M, int N, int K,
                                              float* outF,
                                              bf16_t* outB,
                                              const float* aux,
                                              int ldc) {
    __shared__ bf16_t lA[128 * 32];
    __shared__ bf16_t lB[128 * 32];
    const int tid = threadIdx.x;
    const int l = tid & 63;
    const int w = tid >> 6;
    const int wr = w >> 1, wc = w & 1;
    const long row0 = (long)blockIdx.y * 128;
    const long col0 = (long)blockIdx.x * 128;

    const int f0 = tid, f1 = tid + 256;
    const bf16_t* pa0 = A + (row0 + (f0 >> 2)) * K + (f0 & 3) * 8;
    const bf16_t* pa1 = A + (row0 + (f1 >> 2)) * K + (f1 & 3) * 8;
    const bf16_t* pb0 = B + (col0 + (f0 >> 2)) * K + (f0 & 3) * 8;
    const bf16_t* pb1 = B + (col0 + (f1 >> 2)) * K + (f1 & 3) * 8;

    f32x4 acc[4][4] = {};

    const int aoff = (wr * 64 + (l & 15)) * 32 + (l >> 4) * 8;
    const int boff = (wc * 64 + (l & 15)) * 32 + (l >> 4) * 8;

    for (int k0 = 0; k0 < K; k0 += 32) {
        gload16(pa0 + k0, &lA[f0 * 8]);
        gload16(pa1 + k0, &lA[f1 * 8]);
        gload16(pb0 + k0, &lB[f0 * 8]);
        gload16(pb1 + k0, &lB[f1 * 8]);
        __syncthreads();
        bf16x8 af[4], bfr[4];
        #pragma unroll
        for (int m = 0; m < 4; m++) af[m] = *(const bf16x8*)&lA[aoff + m * 512];
        #pragma unroll
        for (int n = 0; n < 4; n++) bfr[n] = *(const bf16x8*)&lB[boff + n * 512];
        #pragma unroll
        for (int m = 0; m < 4; m++)
            #pragma unroll
            for (int n = 0; n < 4; n++)
                acc[m][n] = __builtin_amdgcn_mfma_f32_16x16x32_bf16(af[m], bfr[n], acc[m][n], 0, 0, 0);
        __syncthreads();
    }

    #pragma unroll
    for (int m = 0; m < 4; m++) {
        const long r0 = row0 + wr * 64 + m * 16 + (l >> 4) * 4;
        #pragma unroll
        for (int n = 0; n < 4; n++) {
            const long c = col0 + wc * 64 + n * 16 + (l & 15);
            f32x4 v = acc[m][n];
            #pragma unroll
            for (int j = 0; j < 4; j++) {
                const long r = r0 + j;
                const float xv = v[j];
                if (EPI == EPI_SIGB) {
                    outF[r * ldc + c] = 1.0f / (1.0f + __expf(-(xv + aux[c])));
                } else if (EPI == EPI_ADDRES) {
                    outF[r * ldc + c] = xv + aux[r * ldc + c];
                } else if (EPI == EPI_IV) {
                    const float px = __shfl_xor(xv, 1);
                    if ((l & 1) == 0)
                        outF[r * ldc + (c >> 1)] = px / (1.0f + __expf(-xv));
                } else {  // EPI_GU
                    const float px = __shfl_xor(xv, 1);
                    if ((l & 1) == 0)
                        outB[r * ldc + (c >> 1)] = (bf16_t)(xv / (1.0f + __expf(-xv)) * px);
                }
            }
        }
    }
}

extern "C" void kernel_launch(void* const* d_in, const int* in_sizes, int n_in,
                              void* d_out, int out_size, void* d_ws, size_t ws_size,
                              hipStream_t stream) {
    const float* x   = (const float*)d_in[0];
    const float* pnw = (const float*)d_in[1];
    const float* cw  = (const float*)d_in[2];
    const float* cb  = (const float*)d_in[3];
    const float* wa  = (const float*)d_in[4];
    const float* wi  = (const float*)d_in[5];
    const float* wv  = (const float*)d_in[6];
    const float* wop = (const float*)d_in[7];
    const float* db  = (const float*)d_in[8];
    const float* fnw = (const float*)d_in[9];
    const float* wgu = (const float*)d_in[10];
    const float* wdn = (const float*)d_in[11];
    float* out = (float*)d_out;

    // ---- workspace layout (total ~129.5 MiB) ----
    char* ws = (char*)d_ws;
    bf16_t* wab   = (bf16_t*)(ws + 0);            // 1024x1024 bf16   [0, 2M)
    bf16_t* wivb  = (bf16_t*)(ws + 2097152);      // 2048x1024 bf16   [2M, 6M)  (i|v interleaved)
    bf16_t* wopb  = (bf16_t*)(ws + 6291456);      // 1024x1024 bf16   [6M, 8M)
    bf16_t* wgub  = (bf16_t*)(ws + 8388608);      // 8192x1024 bf16   [8M, 24M) (gate|up interleaved)
    bf16_t* wdnb  = (bf16_t*)(ws + 25165824);     // 4096x1024 bf16   [24M, 32M)
    bf16_t* hb    = (bf16_t*)(ws + 33554432);     // 8192x1024 bf16   [32M, 48M)  (reused: hn)
    bf16_t* hn    = hb;
    bf16_t* hc    = (bf16_t*)(ws + 50331648);     // 8192x1024 bf16   [48M, 64M)  (reused: rec)
    bf16_t* rec   = hc;
    float*  a_p   = (float*)(ws + 67108864);      // 8192x1024 f32    [64M, 96M)  (reused: cd; act overlays)
    float*  s_p   = (float*)(ws + 100663296);     // 8192x1024 f32    [96M, 128M) (reused: intra)
    bf16_t* act   = (bf16_t*)(ws + 67108864);     // 8192x4096 bf16   [64M, 128M) (after scan)
    float*  cd63  = (float*)(ws + 134217728);     // 2*64*1024 f32
    float*  i63   = (float*)(ws + 134742016);
    float*  carry = (float*)(ws + 135266304);     // end: 135790592 (~129.5 MiB)

    // weight converts / interleaves
    cvt_bf16_k  <<<1024, 256, 0, stream>>>(wa,  wab,  1048576);
    cvt_ileave_k<<<2048, 256, 0, stream>>>(wi,  wv, wivb, 2097152);
    cvt_bf16_k  <<<1024, 256, 0, stream>>>(wop, wopb, 1048576);
    cvt_ileave_k<<<8192, 256, 0, stream>>>(wgu, wgu + 4194304, wgub, 8388608);
    cvt_bf16_k  <<<4096, 256, 0, stream>>>(wdn, wdnb, 4194304);

    // pre-norm + conv
    rmsnorm_k<<<8192, 256, 0, stream>>>(x, pnw, hb);
    conv_k<<<32768, 256, 0, stream>>>(hb, cw, cb, hc);

    // a-plane: sigmoid(h*w_a^T + db);  s-plane: sigmoid(h*w_i^T) * (h*w_v^T)
    gemm_k<EPI_SIGB><<<dim3(8, 64),  256, 0, stream>>>(hc, wab,  8192, 1024, 1024,
                                                       a_p, nullptr, db, 1024);
    gemm_k<EPI_IV>  <<<dim3(16, 64), 256, 0, stream>>>(hc, wivb, 8192, 2048, 1024,
                                                       s_p, nullptr, nullptr, 1024);
    // chunked scan (matches reference's clipped formula), in-place over a_p/s_p
    scan1_k<<<dim3(4, 64, 2), 256, 0, stream>>>(a_p, s_p, cd63, i63);
    scan2_k<<<8, 256, 0, stream>>>(cd63, i63, carry);
    scan3_k<<<32768, 256, 0, stream>>>(a_p, s_p, carry, rec);

    // out_proj + residual -> d_out holds x2
    gemm_k<EPI_ADDRES><<<dim3(8, 64), 256, 0, stream>>>(rec, wopb, 8192, 1024, 1024,
                                                        out, nullptr, x, 1024);
    // ffn
    rmsnorm_k<<<8192, 256, 0, stream>>>(out, fnw, hn);
    gemm_k<EPI_GU><<<dim3(64, 64), 256, 0, stream>>>(hn, wgub, 8192, 8192, 1024,
                                                     nullptr, act, nullptr, 4096);
    // down-proj + residual, in place on d_out
    gemm_k<EPI_ADDRES><<<dim3(8, 64), 256, 0, stream>>>(act, wdnb, 8192, 1024, 4096,
                                                        out, nullptr, out, 1024);
}

// Round 3
// 571.496 us; speedup vs baseline: 1.0360x; 1.0360x over previous
//
#include <hip/hip_runtime.h>

typedef __bf16 bf16_t;
typedef bf16_t bf16x4 __attribute__((ext_vector_type(4)));
typedef bf16_t bf16x8 __attribute__((ext_vector_type(8)));
typedef float f32x4 __attribute__((ext_vector_type(4)));

#define DD 1024
#define TT 4096

__device__ __forceinline__ void gload16(const void* g, void* l) {
    __builtin_amdgcn_global_load_lds(
        (const __attribute__((address_space(1))) void*)g,
        (__attribute__((address_space(3))) void*)l, 16, 0, 0);
}

// ---------------- fp32 -> bf16 convert ----------------
__global__ __launch_bounds__(256) void cvt_bf16_k(const float* __restrict__ s,
                                                  bf16_t* __restrict__ d, int n) {
    int i = (blockIdx.x * 256 + threadIdx.x) * 4;
    if (i < n) {
        const float4 v = *(const float4*)(s + i);
        bf16x4 o;
        o[0] = (bf16_t)v.x; o[1] = (bf16_t)v.y; o[2] = (bf16_t)v.z; o[3] = (bf16_t)v.w;
        *(bf16x4*)(d + i) = o;
    }
}

// ---------------- interleaved convert: dst row 2c = s0 row c, 2c+1 = s1 row c ----------------
__global__ __launch_bounds__(256) void cvt_ileave_k(const float* __restrict__ s0,
                                                    const float* __restrict__ s1,
                                                    bf16_t* __restrict__ d, int total) {
    int i = (blockIdx.x * 256 + threadIdx.x) * 4;
    if (i < total) {
        const int rp = i >> 10, k = i & 1023;
        const int c = rp >> 1;
        const float* src = ((rp & 1) ? s1 : s0) + (long)c * 1024 + k;
        const float4 v = *(const float4*)src;
        bf16x4 o;
        o[0] = (bf16_t)v.x; o[1] = (bf16_t)v.y; o[2] = (bf16_t)v.z; o[3] = (bf16_t)v.w;
        *(bf16x4*)(d + i) = o;
    }
}

// ---------------- rmsnorm (1 block per row, 256 thr x 4 elems), bf16 out ----------------
__global__ __launch_bounds__(256) void rmsnorm_k(const float* __restrict__ x,
                                                 const float* __restrict__ w,
                                                 bf16_t* __restrict__ ob) {
    const long row = blockIdx.x;
    const float* xr = x + row * DD;
    const int t4 = threadIdx.x * 4;
    float4 v = *(const float4*)(xr + t4);
    float s = v.x*v.x + v.y*v.y + v.z*v.z + v.w*v.w;
    #pragma unroll
    for (int off = 1; off < 64; off <<= 1) s += __shfl_xor(s, off);
    __shared__ float red[4];
    if ((threadIdx.x & 63) == 0) red[threadIdx.x >> 6] = s;
    __syncthreads();
    float tot = red[0] + red[1] + red[2] + red[3];
    float sc = rsqrtf(tot * (1.0f / DD) + 1e-6f);
    float4 wv = *(const float4*)(w + t4);
    bf16x4 o;
    o[0] = (bf16_t)(v.x*sc*wv.x); o[1] = (bf16_t)(v.y*sc*wv.y);
    o[2] = (bf16_t)(v.z*sc*wv.z); o[3] = (bf16_t)(v.w*sc*wv.w);
    *(bf16x4*)(ob + row * DD + t4) = o;
}

// ---------------- causal depthwise conv K=4 (bf16 in, bf16 out) ----------------
__global__ __launch_bounds__(256) void conv_k(const bf16_t* __restrict__ h,
                                              const float* __restrict__ cw,
                                              const float* __restrict__ cb,
                                              bf16_t* __restrict__ hc) {
    const long idx = (long)blockIdx.x * 256 + threadIdx.x;  // over B*T*D
    const int d = (int)(idx & (DD - 1));
    const long bt = idx >> 10;
    const int t = (int)(bt & (TT - 1));
    const float w0 = cw[d*4+0], w1 = cw[d*4+1], w2 = cw[d*4+2], w3 = cw[d*4+3];
    const bf16_t* hp = h + bt * DD + d;
    float acc = cb[d] + (float)hp[0] * w3;
    if (t >= 1) acc += (float)hp[-DD]     * w2;
    if (t >= 2) acc += (float)hp[-2*DD]   * w1;
    if (t >= 3) acc += (float)hp[-3*DD]   * w0;
    hc[idx] = (bf16_t)acc;
}

// ---------------- chunked scan pass1: in-place (a,s) -> (cum_decay, intra) ----------------
__global__ __launch_bounds__(256) void scan1_k(float* __restrict__ ap,
                                               float* __restrict__ sp,
                                               float* __restrict__ cd63,
                                               float* __restrict__ i63) {
    const int d = blockIdx.x * 256 + threadIdx.x;  // 0..1023
    const int c = blockIdx.y;                      // chunk 0..63
    const int b = blockIdx.z;                      // batch
    const long rowbase = (long)b * TT + (long)c * 64;
    float la = 0.0f, rs = 0.0f, cdv = 0.0f, it = 0.0f;
    for (int t = 0; t < 64; t++) {
        const long off = (rowbase + t) * DD + d;
        const float a = ap[off];
        const float s = sp[off];
        const float sig = sqrtf(fmaxf(1.0f - a * a, 1e-8f)) * s;
        la += __logf(fmaxf(a, 1e-10f));
        cdv = __expf(la);
        rs += sig / fmaxf(cdv, 1e-10f);
        it = cdv * rs;
        ap[off] = cdv;
        sp[off] = it;
    }
    const long o = ((long)b * 64 + c) * DD + d;
    cd63[o] = cdv;
    i63[o]  = it;
}

// ---------------- pass2: cross-chunk carry (state ENTERING each chunk) ----------------
__global__ __launch_bounds__(256) void scan2_k(const float* __restrict__ cd63,
                                               const float* __restrict__ i63,
                                               float* __restrict__ carry_in) {
    const int g = blockIdx.x * 256 + threadIdx.x;  // 0..2047
    const int b = g >> 10, d = g & (DD - 1);
    float st = 0.0f;
    for (int c = 0; c < 64; c++) {
        const long o = ((long)b * 64 + c) * DD + d;
        carry_in[o] = st;
        st = i63[o] + cd63[o] * st;
    }
}

// ---------------- pass3: rec = bf16(intra + cd * carry_in) ----------------
__global__ __launch_bounds__(256) void scan3_k(const float* __restrict__ cd,
                                               const float* __restrict__ intra,
                                               const float* __restrict__ carry_in,
                                               bf16_t* __restrict__ rec) {
    const long idx = (long)blockIdx.x * 256 + threadIdx.x;  // B*T*D
    const int d = (int)(idx & (DD - 1));
    const long row = idx >> 10;
    const long b = row >> 12;
    const int t = (int)(row & (TT - 1));
    const int c = t >> 6;
    const float st = carry_in[((b * 64) + c) * DD + d];
    rec[idx] = (bf16_t)(intra[idx] + cd[idx] * st);
}

// ---------------- bf16 GEMM, C = A(M,K) * B(N,K)^T ----------------
// 256x256 tile, BK=64, 8 waves (2M x 4N), 4-phase schedule, counted vmcnt,
// T2 LDS swizzle (pre-swizzled global src + swizzled ds_read), T5 setprio,
// T1 XCD-bijective grid swizzle.  Requires 128 KiB dynamic LDS.
enum { EPI_SIGB = 0, EPI_ADDRES = 1, EPI_IV = 2, EPI_GU = 3 };

template<int EPI>
__global__ __launch_bounds__(512, 2) void gemm8p_k(const bf16_t* __restrict__ Ag,
                                                   const bf16_t* __restrict__ Bg,
                                                   int M, int N, int K,
                                                   float* outF, bf16_t* outB,
                                                   const float* aux, int ldc) {
    extern __shared__ bf16_t smem[];  // [2][A 256x64 | B 256x64] = 65536 bf16
    const int tid = threadIdx.x;
    const int l = tid & 63;
    const int w = tid >> 6;          // wave 0..7
    const int wm = w >> 2, wn = w & 3;

    // XCD-aware swizzle (all grids have nb % 8 == 0)
    const int gx = gridDim.x;
    const int nb = gx * gridDim.y;
    const int lin = blockIdx.y * gx + blockIdx.x;
    const int sw = (lin & 7) * (nb >> 3) + (lin >> 3);
    const long row0 = (long)(sw / gx) * 256;
    const long col0 = (long)(sw % gx) * 256;

    // staging: each wave stages 32 rows of A and of B per K-tile (4 loads each).
    // lane -> (row srow, swizzled col scol); LDS dest is linear, source pre-swizzled.
    const int srow = l >> 3;
    const int scol = ((l & 7) ^ srow) * 8;
    const long aBase = row0 + srow;
    const long bBase = col0 + srow;

    const int NT = K >> 6;
    f32x4 acc[8][4] = {};

    // prologue: stage tile 0 into buf 0
    #pragma unroll
    for (int i = 0; i < 4; i++) {
        const int R0 = w * 32 + i * 8;
        gload16(Ag + (aBase + R0) * (long)K + scol, &smem[R0 * 64]);
        gload16(Bg + (bBase + R0) * (long)K + scol, &smem[16384 + R0 * 64]);
    }

    const int lq = (l >> 4) * 8;   // k sub-offset for fragments
    const int rA = wm * 128 + (l & 15);
    const int rB = wn * 64 + (l & 15);

    for (int t = 0; t < NT; t++) {
        const int cb = (t & 1) * 32768;
        const int ob = 32768 - cb;
        const long kg = (long)(t + 1) * 64 + scol;
        const int R0w = w * 32;
        bf16x8 Bf[2][4], Af[4];

        // ---- phase 0: stage part0(t+1), counted vmcnt, read B(all)+A[mh0,kk0], 16 MFMA
        if (t + 1 < NT) {
            gload16(Bg + (bBase + R0w) * (long)K + kg, &smem[ob + 16384 + R0w * 64]);
            gload16(Ag + (aBase + R0w) * (long)K + kg, &smem[ob + R0w * 64]);
            asm volatile("s_waitcnt vmcnt(2)" ::: "memory");
        } else {
            asm volatile("s_waitcnt vmcnt(0)" ::: "memory");
        }
        asm volatile("s_barrier" ::: "memory");
        #pragma unroll
        for (int n = 0; n < 4; n++) {
            const int r = rB + n * 16;
            const int bo0 = (lq * 2) ^ ((r & 7) << 4);
            Bf[0][n] = *(const bf16x8*)&smem[cb + 16384 + r * 64 + (bo0 >> 1)];
            Bf[1][n] = *(const bf16x8*)&smem[cb + 16384 + r * 64 + ((bo0 ^ 64) >> 1)];
        }
        #pragma unroll
        for (int m = 0; m < 4; m++) {
            const int r = rA + m * 16;
            Af[m] = *(const bf16x8*)&smem[cb + r * 64 + (((lq * 2) ^ ((r & 7) << 4)) >> 1)];
        }
        __builtin_amdgcn_s_setprio(1);
        #pragma unroll
        for (int m = 0; m < 4; m++)
            #pragma unroll
            for (int n = 0; n < 4; n++)
                acc[m][n] = __builtin_amdgcn_mfma_f32_16x16x32_bf16(Af[m], Bf[0][n], acc[m][n], 0, 0, 0);
        __builtin_amdgcn_s_setprio(0);
        asm volatile("s_barrier" ::: "memory");

        // ---- phase 1: read A[mh1,kk0], stage part1, 16 MFMA
        #pragma unroll
        for (int m = 0; m < 4; m++) {
            const int r = rA + 64 + m * 16;
            Af[m] = *(const bf16x8*)&smem[cb + r * 64 + (((lq * 2) ^ ((r & 7) << 4)) >> 1)];
        }
        if (t + 1 < NT) {
            gload16(Bg + (bBase + R0w + 8) * (long)K + kg, &smem[ob + 16384 + (R0w + 8) * 64]);
            gload16(Ag + (aBase + R0w + 8) * (long)K + kg, &smem[ob + (R0w + 8) * 64]);
        }
        asm volatile("s_barrier" ::: "memory");
        __builtin_amdgcn_s_setprio(1);
        #pragma unroll
        for (int m = 0; m < 4; m++)
            #pragma unroll
            for (int n = 0; n < 4; n++)
                acc[m + 4][n] = __builtin_amdgcn_mfma_f32_16x16x32_bf16(Af[m], Bf[0][n], acc[m + 4][n], 0, 0, 0);
        __builtin_amdgcn_s_setprio(0);
        asm volatile("s_barrier" ::: "memory");

        // ---- phase 2: read A[mh0,kk1], stage part2, 16 MFMA
        #pragma unroll
        for (int m = 0; m < 4; m++) {
            const int r = rA + m * 16;
            Af[m] = *(const bf16x8*)&smem[cb + r * 64 + ((((lq + 32) * 2) ^ ((r & 7) << 4)) >> 1)];
        }
        if (t + 1 < NT) {
            gload16(Bg + (bBase + R0w + 16) * (long)K + kg, &smem[ob + 16384 + (R0w + 16) * 64]);
            gload16(Ag + (aBase + R0w + 16) * (long)K + kg, &smem[ob + (R0w + 16) * 64]);
        }
        asm volatile("s_barrier" ::: "memory");
        __builtin_amdgcn_s_setprio(1);
        #pragma unroll
        for (int m = 0; m < 4; m++)
            #pragma unroll
            for (int n = 0; n < 4; n++)
                acc[m][n] = __builtin_amdgcn_mfma_f32_16x16x32_bf16(Af[m], Bf[1][n], acc[m][n], 0, 0, 0);
        __builtin_amdgcn_s_setprio(0);
        asm volatile("s_barrier" ::: "memory");

        // ---- phase 3: read A[mh1,kk1], stage part3, 16 MFMA
        #pragma unroll
        for (int m = 0; m < 4; m++) {
            const int r = rA + 64 + m * 16;
            Af[m] = *(const bf16x8*)&smem[cb + r * 64 + ((((lq + 32) * 2) ^ ((r & 7) << 4)) >> 1)];
        }
        if (t + 1 < NT) {
            gload16(Bg + (bBase + R0w + 24) * (long)K + kg, &smem[ob + 16384 + (R0w + 24) * 64]);
            gload16(Ag + (aBase + R0w + 24) * (long)K + kg, &smem[ob + (R0w + 24) * 64]);
        }
        asm volatile("s_barrier" ::: "memory");
        __builtin_amdgcn_s_setprio(1);
        #pragma unroll
        for (int m = 0; m < 4; m++)
            #pragma unroll
            for (int n = 0; n < 4; n++)
                acc[m + 4][n] = __builtin_amdgcn_mfma_f32_16x16x32_bf16(Af[m], Bf[1][n], acc[m + 4][n], 0, 0, 0);
        __builtin_amdgcn_s_setprio(0);
        asm volatile("s_barrier" ::: "memory");
    }

    // ---- epilogue ----
    #pragma unroll
    for (int m = 0; m < 8; m++) {
        const long r0 = row0 + wm * 128 + m * 16 + (l >> 4) * 4;
        #pragma unroll
        for (int n = 0; n < 4; n++) {
            const long cc = col0 + wn * 64 + n * 16 + (l & 15);
            f32x4 v = acc[m][n];
            #pragma unroll
            for (int j = 0; j < 4; j++) {
                const long r = r0 + j;
                const float xv = v[j];
                if (EPI == EPI_SIGB) {
                    outF[r * ldc + cc] = 1.0f / (1.0f + __expf(-(xv + aux[cc])));
                } else if (EPI == EPI_ADDRES) {
                    outF[r * ldc + cc] = xv + aux[r * ldc + cc];
                } else if (EPI == EPI_IV) {
                    const float px = __shfl_xor(xv, 1);
                    if ((l & 1) == 0)
                        outF[r * ldc + (cc >> 1)] = px / (1.0f + __expf(-xv));
                } else {  // EPI_GU
                    const float px = __shfl_xor(xv, 1);
                    if ((l & 1) == 0)
                        outB[r * ldc + (cc >> 1)] = (bf16_t)(xv / (1.0f + __expf(-xv)) * px);
                }
            }
        }
    }
}

extern "C" void kernel_launch(void* const* d_in, const int* in_sizes, int n_in,
                              void* d_out, int out_size, void* d_ws, size_t ws_size,
                              hipStream_t stream) {
    const float* x   = (const float*)d_in[0];
    const float* pnw = (const float*)d_in[1];
    const float* cw  = (const float*)d_in[2];
    const float* cb  = (const float*)d_in[3];
    const float* wa  = (const float*)d_in[4];
    const float* wi  = (const float*)d_in[5];
    const float* wv  = (const float*)d_in[6];
    const float* wop = (const float*)d_in[7];
    const float* db  = (const float*)d_in[8];
    const float* fnw = (const float*)d_in[9];
    const float* wgu = (const float*)d_in[10];
    const float* wdn = (const float*)d_in[11];
    float* out = (float*)d_out;

    // ---- workspace layout (total ~129.5 MiB) ----
    char* ws = (char*)d_ws;
    bf16_t* wab   = (bf16_t*)(ws + 0);            // 1024x1024 bf16
    bf16_t* wivb  = (bf16_t*)(ws + 2097152);      // 2048x1024 bf16 (i|v interleaved)
    bf16_t* wopb  = (bf16_t*)(ws + 6291456);      // 1024x1024 bf16
    bf16_t* wgub  = (bf16_t*)(ws + 8388608);      // 8192x1024 bf16 (gate|up interleaved)
    bf16_t* wdnb  = (bf16_t*)(ws + 25165824);     // 4096x1024 bf16
    bf16_t* hb    = (bf16_t*)(ws + 33554432);     // 8192x1024 bf16 (reused: hn)
    bf16_t* hn    = hb;
    bf16_t* hc    = (bf16_t*)(ws + 50331648);     // 8192x1024 bf16 (reused: rec)
    bf16_t* rec   = hc;
    float*  a_p   = (float*)(ws + 67108864);      // 8192x1024 f32 (reused by act)
    float*  s_p   = (float*)(ws + 100663296);     // 8192x1024 f32
    bf16_t* act   = (bf16_t*)(ws + 67108864);     // 8192x4096 bf16 (after scan)
    float*  cd63  = (float*)(ws + 134217728);
    float*  i63   = (float*)(ws + 134742016);
    float*  carry = (float*)(ws + 135266304);

    const int LDSB = 131072;
    hipFuncSetAttribute((const void*)gemm8p_k<EPI_SIGB>,   hipFuncAttributeMaxDynamicSharedMemorySize, LDSB);
    hipFuncSetAttribute((const void*)gemm8p_k<EPI_ADDRES>, hipFuncAttributeMaxDynamicSharedMemorySize, LDSB);
    hipFuncSetAttribute((const void*)gemm8p_k<EPI_IV>,     hipFuncAttributeMaxDynamicSharedMemorySize, LDSB);
    hipFuncSetAttribute((const void*)gemm8p_k<EPI_GU>,     hipFuncAttributeMaxDynamicSharedMemorySize, LDSB);

    // weight converts / interleaves
    cvt_bf16_k  <<<1024, 256, 0, stream>>>(wa,  wab,  1048576);
    cvt_ileave_k<<<2048, 256, 0, stream>>>(wi,  wv, wivb, 2097152);
    cvt_bf16_k  <<<1024, 256, 0, stream>>>(wop, wopb, 1048576);
    cvt_ileave_k<<<8192, 256, 0, stream>>>(wgu, wgu + 4194304, wgub, 8388608);
    cvt_bf16_k  <<<4096, 256, 0, stream>>>(wdn, wdnb, 4194304);

    // pre-norm + conv
    rmsnorm_k<<<8192, 256, 0, stream>>>(x, pnw, hb);
    conv_k<<<32768, 256, 0, stream>>>(hb, cw, cb, hc);

    // a-plane: sigmoid(h*w_a^T + db);  s-plane: sigmoid(h*w_i^T) * (h*w_v^T)
    gemm8p_k<EPI_SIGB><<<dim3(4, 32),  512, LDSB, stream>>>(hc, wab,  8192, 1024, 1024,
                                                            a_p, nullptr, db, 1024);
    gemm8p_k<EPI_IV>  <<<dim3(8, 32),  512, LDSB, stream>>>(hc, wivb, 8192, 2048, 1024,
                                                            s_p, nullptr, nullptr, 1024);
    // chunked scan (matches reference's clipped formula), in-place over a_p/s_p
    scan1_k<<<dim3(4, 64, 2), 256, 0, stream>>>(a_p, s_p, cd63, i63);
    scan2_k<<<8, 256, 0, stream>>>(cd63, i63, carry);
    scan3_k<<<32768, 256, 0, stream>>>(a_p, s_p, carry, rec);

    // out_proj + residual -> d_out holds x2
    gemm8p_k<EPI_ADDRES><<<dim3(4, 32), 512, LDSB, stream>>>(rec, wopb, 8192, 1024, 1024,
                                                             out, nullptr, x, 1024);
    // ffn
    rmsnorm_k<<<8192, 256, 0, stream>>>(out, fnw, hn);
    gemm8p_k<EPI_GU><<<dim3(32, 32), 512, LDSB, stream>>>(hn, wgub, 8192, 8192, 1024,
                                                          nullptr, act, nullptr, 4096);
    // down-proj + residual, in place on d_out
    gemm8p_k<EPI_ADDRES><<<dim3(4, 32), 512, LDSB, stream>>>(act, wdnb, 8192, 1024, 4096,
                                                             out, nullptr, out, 1024);
}

// Round 4
// 560.980 us; speedup vs baseline: 1.0554x; 1.0187x over previous
//
#include <hip/hip_runtime.h>

typedef __bf16 bf16_t;
typedef bf16_t bf16x4 __attribute__((ext_vector_type(4)));
typedef bf16_t bf16x8 __attribute__((ext_vector_type(8)));
typedef float f32x4 __attribute__((ext_vector_type(4)));

#define DD 1024
#define TT 4096

__device__ __forceinline__ void gload16(const void* g, void* l) {
    __builtin_amdgcn_global_load_lds(
        (const __attribute__((address_space(1))) void*)g,
        (__attribute__((address_space(3))) void*)l, 16, 0, 0);
}

// ---------------- fp32 -> bf16 convert ----------------
__global__ __launch_bounds__(256) void cvt_bf16_k(const float* __restrict__ s,
                                                  bf16_t* __restrict__ d, int n) {
    int i = (blockIdx.x * 256 + threadIdx.x) * 4;
    if (i < n) {
        const float4 v = *(const float4*)(s + i);
        bf16x4 o;
        o[0] = (bf16_t)v.x; o[1] = (bf16_t)v.y; o[2] = (bf16_t)v.z; o[3] = (bf16_t)v.w;
        *(bf16x4*)(d + i) = o;
    }
}

// ---------------- interleaved convert: dst row 2c = s0 row c, 2c+1 = s1 row c ----------------
__global__ __launch_bounds__(256) void cvt_ileave_k(const float* __restrict__ s0,
                                                    const float* __restrict__ s1,
                                                    bf16_t* __restrict__ d, int total) {
    int i = (blockIdx.x * 256 + threadIdx.x) * 4;
    if (i < total) {
        const int rp = i >> 10, k = i & 1023;
        const int c = rp >> 1;
        const float* src = ((rp & 1) ? s1 : s0) + (long)c * 1024 + k;
        const float4 v = *(const float4*)src;
        bf16x4 o;
        o[0] = (bf16_t)v.x; o[1] = (bf16_t)v.y; o[2] = (bf16_t)v.z; o[3] = (bf16_t)v.w;
        *(bf16x4*)(d + i) = o;
    }
}

// ---------------- rmsnorm (1 block per row, 256 thr x 4 elems), bf16 out ----------------
__global__ __launch_bounds__(256) void rmsnorm_k(const float* __restrict__ x,
                                                 const float* __restrict__ w,
                                                 bf16_t* __restrict__ ob) {
    const long row = blockIdx.x;
    const float* xr = x + row * DD;
    const int t4 = threadIdx.x * 4;
    float4 v = *(const float4*)(xr + t4);
    float s = v.x*v.x + v.y*v.y + v.z*v.z + v.w*v.w;
    #pragma unroll
    for (int off = 1; off < 64; off <<= 1) s += __shfl_xor(s, off);
    __shared__ float red[4];
    if ((threadIdx.x & 63) == 0) red[threadIdx.x >> 6] = s;
    __syncthreads();
    float tot = red[0] + red[1] + red[2] + red[3];
    float sc = rsqrtf(tot * (1.0f / DD) + 1e-6f);
    float4 wv = *(const float4*)(w + t4);
    bf16x4 o;
    o[0] = (bf16_t)(v.x*sc*wv.x); o[1] = (bf16_t)(v.y*sc*wv.y);
    o[2] = (bf16_t)(v.z*sc*wv.z); o[3] = (bf16_t)(v.w*sc*wv.w);
    *(bf16x4*)(ob + row * DD + t4) = o;
}

// ---------------- causal depthwise conv K=4 (bf16 in, bf16 out) ----------------
__global__ __launch_bounds__(256) void conv_k(const bf16_t* __restrict__ h,
                                              const float* __restrict__ cw,
                                              const float* __restrict__ cb,
                                              bf16_t* __restrict__ hc) {
    const long idx = (long)blockIdx.x * 256 + threadIdx.x;  // over B*T*D
    const int d = (int)(idx & (DD - 1));
    const long bt = idx >> 10;
    const int t = (int)(bt & (TT - 1));
    const float w0 = cw[d*4+0], w1 = cw[d*4+1], w2 = cw[d*4+2], w3 = cw[d*4+3];
    const bf16_t* hp = h + bt * DD + d;
    float acc = cb[d] + (float)hp[0] * w3;
    if (t >= 1) acc += (float)hp[-DD]     * w2;
    if (t >= 2) acc += (float)hp[-2*DD]   * w1;
    if (t >= 3) acc += (float)hp[-3*DD]   * w0;
    hc[idx] = (bf16_t)acc;
}

// ---------------- chunked scan pass1: in-place (a,s) -> (cum_decay, intra) ----------------
__global__ __launch_bounds__(256) void scan1_k(float* __restrict__ ap,
                                               float* __restrict__ sp,
                                               float* __restrict__ cd63,
                                               float* __restrict__ i63) {
    const int d = blockIdx.x * 256 + threadIdx.x;  // 0..1023
    const int c = blockIdx.y;                      // chunk 0..63
    const int b = blockIdx.z;                      // batch
    const long rowbase = (long)b * TT + (long)c * 64;
    float la = 0.0f, rs = 0.0f, cdv = 0.0f, it = 0.0f;
    for (int t = 0; t < 64; t++) {
        const long off = (rowbase + t) * DD + d;
        const float a = ap[off];
        const float s = sp[off];
        const float sig = sqrtf(fmaxf(1.0f - a * a, 1e-8f)) * s;
        la += __logf(fmaxf(a, 1e-10f));
        cdv = __expf(la);
        rs += sig / fmaxf(cdv, 1e-10f);
        it = cdv * rs;
        ap[off] = cdv;
        sp[off] = it;
    }
    const long o = ((long)b * 64 + c) * DD + d;
    cd63[o] = cdv;
    i63[o]  = it;
}

// ---------------- pass2: cross-chunk carry (state ENTERING each chunk) ----------------
__global__ __launch_bounds__(256) void scan2_k(const float* __restrict__ cd63,
                                               const float* __restrict__ i63,
                                               float* __restrict__ carry_in) {
    const int g = blockIdx.x * 256 + threadIdx.x;  // 0..2047
    const int b = g >> 10, d = g & (DD - 1);
    float st = 0.0f;
    for (int c = 0; c < 64; c++) {
        const long o = ((long)b * 64 + c) * DD + d;
        carry_in[o] = st;
        st = i63[o] + cd63[o] * st;
    }
}

// ---------------- pass3: rec = bf16(intra + cd * carry_in) ----------------
__global__ __launch_bounds__(256) void scan3_k(const float* __restrict__ cd,
                                               const float* __restrict__ intra,
                                               const float* __restrict__ carry_in,
                                               bf16_t* __restrict__ rec) {
    const long idx = (long)blockIdx.x * 256 + threadIdx.x;  // B*T*D
    const int d = (int)(idx & (DD - 1));
    const long row = idx >> 10;
    const long b = row >> 12;
    const int t = (int)(row & (TT - 1));
    const int c = t >> 6;
    const float st = carry_in[((b * 64) + c) * DD + d];
    rec[idx] = (bf16_t)(intra[idx] + cd[idx] * st);
}

// ---------------- bf16 GEMM, C = A(M,K) * B(N,K)^T ----------------
// 256x256 tile, BK=64, 8 waves (2M x 4N), 4-phase schedule.
// T4 counted vmcnt with derived load-slot schedule:
//   tile τ's B loads issue at iter τ-2 ph2/ph3 (into the then-current read
//   buffer's B region, dead after its ph0), A loads at iter τ-1 ph0/ph1.
//   vmcnt(6) once per K-tile at ph0 drains all of tile t (its youngest load
//   sits at outstanding position 7-8). Every load gets >=3 phases of slack.
// T2 swizzle (pre-swizzled global src + XOR'd ds_read), T5 setprio,
// T1 XCD chunk with column-major order inside the chunk (L2 blocking).
enum { EPI_SIGB = 0, EPI_ADDRES = 1, EPI_IV = 2, EPI_GU = 3 };

template<int EPI>
__global__ __launch_bounds__(512, 2) void gemm8p_k(const bf16_t* __restrict__ Ag,
                                                   const bf16_t* __restrict__ Bg,
                                                   int M, int N, int K,
                                                   float* outF, bf16_t* outB,
                                                   const float* aux, int ldc) {
    extern __shared__ bf16_t smem[];  // [2][A 256x64 | B 256x64] = 65536 bf16
    const int tid = threadIdx.x;
    const int l = tid & 63;
    const int w = tid >> 6;          // wave 0..7
    const int wm = w >> 2, wn = w & 3;

    // XCD-aware mapping: xcd = lin&7 owns a contiguous chunk; within the
    // chunk order column-major so concurrent blocks share A rows AND B cols.
    const int gx = gridDim.x;
    const int gy = gridDim.y;
    const int lin = blockIdx.y * gx + blockIdx.x;
    long row0, col0;
    if ((gy & 7) == 0) {
        const int rpc = gy >> 3;          // row-panels per XCD chunk
        const int q = lin >> 3;
        row0 = (long)((lin & 7) * rpc + q % rpc) * 256;
        col0 = (long)(q / rpc) * 256;
    } else {
        row0 = (long)blockIdx.y * 256;
        col0 = (long)blockIdx.x * 256;
    }

    // staging: wave w stages rows [w*32, w*32+32) of A and B per K-tile.
    // lane -> (row srow, swizzled col scol); LDS dest linear, source pre-swizzled.
    const int srow = l >> 3;
    const int scol = ((l & 7) ^ srow) * 8;
    const long aBase = row0 + srow;
    const long bBase = col0 + srow;

    const int NT = K >> 6;
    f32x4 acc[8][4] = {};

    // prologue: tile0 B+A into buf0; tile1 B into buf1
    #pragma unroll
    for (int i = 0; i < 4; i++) {
        const int R0 = w * 32 + i * 8;
        gload16(Bg + (bBase + R0) * (long)K + scol, &smem[16384 + R0 * 64]);
    }
    #pragma unroll
    for (int i = 0; i < 4; i++) {
        const int R0 = w * 32 + i * 8;
        gload16(Ag + (aBase + R0) * (long)K + scol, &smem[R0 * 64]);
    }
    #pragma unroll
    for (int i = 0; i < 4; i++) {
        const int R0 = w * 32 + i * 8;
        gload16(Bg + (bBase + R0) * (long)K + 64 + scol, &smem[32768 + 16384 + R0 * 64]);
    }

    const int lq = (l >> 4) * 8;   // k sub-offset for fragments
    const int rA = wm * 128 + (l & 15);
    const int rB = wn * 64 + (l & 15);

    for (int t = 0; t < NT; t++) {
        const int cb = (t & 1) * 32768;
        const int ob = 32768 - cb;
        const int R0w = w * 32;
        const long kg1 = (long)(t + 1) * 64 + scol;
        const long kg2 = (long)(t + 2) * 64 + scol;
        bf16x8 Bf[2][4], Af[4];

        // ---- phase 0: issue (t+1)A01; vmcnt; barrier; read B(all)+A[mh0,kk0]; MFMA
        if (t + 1 < NT) {
            gload16(Ag + (aBase + R0w) * (long)K + kg1, &smem[ob + R0w * 64]);
            gload16(Ag + (aBase + R0w + 8) * (long)K + kg1, &smem[ob + (R0w + 8) * 64]);
        }
        if (t == NT - 1) { asm volatile("s_waitcnt vmcnt(0)" ::: "memory"); }
        else             { asm volatile("s_waitcnt vmcnt(6)" ::: "memory"); }
        asm volatile("s_barrier" ::: "memory");
        #pragma unroll
        for (int n = 0; n < 4; n++) {
            const int r = rB + n * 16;
            const int bo0 = (lq * 2) ^ ((r & 7) << 4);
            Bf[0][n] = *(const bf16x8*)&smem[cb + 16384 + r * 64 + (bo0 >> 1)];
            Bf[1][n] = *(const bf16x8*)&smem[cb + 16384 + r * 64 + ((bo0 ^ 64) >> 1)];
        }
        #pragma unroll
        for (int m = 0; m < 4; m++) {
            const int r = rA + m * 16;
            Af[m] = *(const bf16x8*)&smem[cb + r * 64 + (((lq * 2) ^ ((r & 7) << 4)) >> 1)];
        }
        __builtin_amdgcn_s_setprio(1);
        #pragma unroll
        for (int m = 0; m < 4; m++)
            #pragma unroll
            for (int n = 0; n < 4; n++)
                acc[m][n] = __builtin_amdgcn_mfma_f32_16x16x32_bf16(Af[m], Bf[0][n], acc[m][n], 0, 0, 0);
        __builtin_amdgcn_s_setprio(0);
        asm volatile("s_barrier" ::: "memory");

        // ---- phase 1: read A[mh1,kk0]; issue (t+1)A23; barrier; MFMA
        #pragma unroll
        for (int m = 0; m < 4; m++) {
            const int r = rA + 64 + m * 16;
            Af[m] = *(const bf16x8*)&smem[cb + r * 64 + (((lq * 2) ^ ((r & 7) << 4)) >> 1)];
        }
        if (t + 1 < NT) {
            gload16(Ag + (aBase + R0w + 16) * (long)K + kg1, &smem[ob + (R0w + 16) * 64]);
            gload16(Ag + (aBase + R0w + 24) * (long)K + kg1, &smem[ob + (R0w + 24) * 64]);
        }
        asm volatile("s_barrier" ::: "memory");
        __builtin_amdgcn_s_setprio(1);
        #pragma unroll
        for (int m = 0; m < 4; m++)
            #pragma unroll
            for (int n = 0; n < 4; n++)
                acc[m + 4][n] = __builtin_amdgcn_mfma_f32_16x16x32_bf16(Af[m], Bf[0][n], acc[m + 4][n], 0, 0, 0);
        __builtin_amdgcn_s_setprio(0);
        asm volatile("s_barrier" ::: "memory");

        // ---- phase 2: read A[mh0,kk1]; issue (t+2)B01 into cb's dead B region; MFMA
        #pragma unroll
        for (int m = 0; m < 4; m++) {
            const int r = rA + m * 16;
            Af[m] = *(const bf16x8*)&smem[cb + r * 64 + ((((lq + 32) * 2) ^ ((r & 7) << 4)) >> 1)];
        }
        if (t + 2 < NT) {
            gload16(Bg + (bBase + R0w) * (long)K + kg2, &smem[cb + 16384 + R0w * 64]);
            gload16(Bg + (bBase + R0w + 8) * (long)K + kg2, &smem[cb + 16384 + (R0w + 8) * 64]);
        }
        asm volatile("s_barrier" ::: "memory");
        __builtin_amdgcn_s_setprio(1);
        #pragma unroll
        for (int m = 0; m < 4; m++)
            #pragma unroll
            for (int n = 0; n < 4; n++)
                acc[m][n] = __builtin_amdgcn_mfma_f32_16x16x32_bf16(Af[m], Bf[1][n], acc[m][n], 0, 0, 0);
        __builtin_amdgcn_s_setprio(0);
        asm volatile("s_barrier" ::: "memory");

        // ---- phase 3: read A[mh1,kk1]; issue (t+2)B23; MFMA
        #pragma unroll
        for (int m = 0; m < 4; m++) {
            const int r = rA + 64 + m * 16;
            Af[m] = *(const bf16x8*)&smem[cb + r * 64 + ((((lq + 32) * 2) ^ ((r & 7) << 4)) >> 1)];
        }
        if (t + 2 < NT) {
            gload16(Bg + (bBase + R0w + 16) * (long)K + kg2, &smem[cb + 16384 + (R0w + 16) * 64]);
            gload16(Bg + (bBase + R0w + 24) * (long)K + kg2, &smem[cb + 16384 + (R0w + 24) * 64]);
        }
        asm volatile("s_barrier" ::: "memory");
        __builtin_amdgcn_s_setprio(1);
        #pragma unroll
        for (int m = 0; m < 4; m++)
            #pragma unroll
            for (int n = 0; n < 4; n++)
                acc[m + 4][n] = __builtin_amdgcn_mfma_f32_16x16x32_bf16(Af[m], Bf[1][n], acc[m + 4][n], 0, 0, 0);
        __builtin_amdgcn_s_setprio(0);
        asm volatile("s_barrier" ::: "memory");
    }

    // ---- epilogue ----
    #pragma unroll
    for (int m = 0; m < 8; m++) {
        const long r0 = row0 + wm * 128 + m * 16 + (l >> 4) * 4;
        #pragma unroll
        for (int n = 0; n < 4; n++) {
            const long cc = col0 + wn * 64 + n * 16 + (l & 15);
            f32x4 v = acc[m][n];
            #pragma unroll
            for (int j = 0; j < 4; j++) {
                const long r = r0 + j;
                const float xv = v[j];
                if (EPI == EPI_SIGB) {
                    outF[r * ldc + cc] = 1.0f / (1.0f + __expf(-(xv + aux[cc])));
                } else if (EPI == EPI_ADDRES) {
                    outF[r * ldc + cc] = xv + aux[r * ldc + cc];
                } else if (EPI == EPI_IV) {
                    const float px = __shfl_xor(xv, 1);
                    if ((l & 1) == 0)
                        outF[r * ldc + (cc >> 1)] = px / (1.0f + __expf(-xv));
                } else {  // EPI_GU
                    const float px = __shfl_xor(xv, 1);
                    if ((l & 1) == 0)
                        outB[r * ldc + (cc >> 1)] = (bf16_t)(xv / (1.0f + __expf(-xv)) * px);
                }
            }
        }
    }
}

extern "C" void kernel_launch(void* const* d_in, const int* in_sizes, int n_in,
                              void* d_out, int out_size, void* d_ws, size_t ws_size,
                              hipStream_t stream) {
    const float* x   = (const float*)d_in[0];
    const float* pnw = (const float*)d_in[1];
    const float* cw  = (const float*)d_in[2];
    const float* cb  = (const float*)d_in[3];
    const float* wa  = (const float*)d_in[4];
    const float* wi  = (const float*)d_in[5];
    const float* wv  = (const float*)d_in[6];
    const float* wop = (const float*)d_in[7];
    const float* db  = (const float*)d_in[8];
    const float* fnw = (const float*)d_in[9];
    const float* wgu = (const float*)d_in[10];
    const float* wdn = (const float*)d_in[11];
    float* out = (float*)d_out;

    // ---- workspace layout (total ~129.5 MiB) ----
    char* ws = (char*)d_ws;
    bf16_t* wab   = (bf16_t*)(ws + 0);            // 1024x1024 bf16
    bf16_t* wivb  = (bf16_t*)(ws + 2097152);      // 2048x1024 bf16 (i|v interleaved)
    bf16_t* wopb  = (bf16_t*)(ws + 6291456);      // 1024x1024 bf16
    bf16_t* wgub  = (bf16_t*)(ws + 8388608);      // 8192x1024 bf16 (gate|up interleaved)
    bf16_t* wdnb  = (bf16_t*)(ws + 25165824);     // 4096x1024 bf16
    bf16_t* hb    = (bf16_t*)(ws + 33554432);     // 8192x1024 bf16 (reused: hn)
    bf16_t* hn    = hb;
    bf16_t* hc    = (bf16_t*)(ws + 50331648);     // 8192x1024 bf16 (reused: rec)
    bf16_t* rec   = hc;
    float*  a_p   = (float*)(ws + 67108864);      // 8192x1024 f32 (reused by act)
    float*  s_p   = (float*)(ws + 100663296);     // 8192x1024 f32
    bf16_t* act   = (bf16_t*)(ws + 67108864);     // 8192x4096 bf16 (after scan)
    float*  cd63  = (float*)(ws + 134217728);
    float*  i63   = (float*)(ws + 134742016);
    float*  carry = (float*)(ws + 135266304);

    const int LDSB = 131072;
    hipFuncSetAttribute((const void*)gemm8p_k<EPI_SIGB>,   hipFuncAttributeMaxDynamicSharedMemorySize, LDSB);
    hipFuncSetAttribute((const void*)gemm8p_k<EPI_ADDRES>, hipFuncAttributeMaxDynamicSharedMemorySize, LDSB);
    hipFuncSetAttribute((const void*)gemm8p_k<EPI_IV>,     hipFuncAttributeMaxDynamicSharedMemorySize, LDSB);
    hipFuncSetAttribute((const void*)gemm8p_k<EPI_GU>,     hipFuncAttributeMaxDynamicSharedMemorySize, LDSB);

    // weight converts / interleaves
    cvt_bf16_k  <<<1024, 256, 0, stream>>>(wa,  wab,  1048576);
    cvt_ileave_k<<<2048, 256, 0, stream>>>(wi,  wv, wivb, 2097152);
    cvt_bf16_k  <<<1024, 256, 0, stream>>>(wop, wopb, 1048576);
    cvt_ileave_k<<<8192, 256, 0, stream>>>(wgu, wgu + 4194304, wgub, 8388608);
    cvt_bf16_k  <<<4096, 256, 0, stream>>>(wdn, wdnb, 4194304);

    // pre-norm + conv
    rmsnorm_k<<<8192, 256, 0, stream>>>(x, pnw, hb);
    conv_k<<<32768, 256, 0, stream>>>(hb, cw, cb, hc);

    // a-plane: sigmoid(h*w_a^T + db);  s-plane: sigmoid(h*w_i^T) * (h*w_v^T)
    gemm8p_k<EPI_SIGB><<<dim3(4, 32),  512, LDSB, stream>>>(hc, wab,  8192, 1024, 1024,
                                                            a_p, nullptr, db, 1024);
    gemm8p_k<EPI_IV>  <<<dim3(8, 32),  512, LDSB, stream>>>(hc, wivb, 8192, 2048, 1024,
                                                            s_p, nullptr, nullptr, 1024);
    // chunked scan (matches reference's clipped formula), in-place over a_p/s_p
    scan1_k<<<dim3(4, 64, 2), 256, 0, stream>>>(a_p, s_p, cd63, i63);
    scan2_k<<<8, 256, 0, stream>>>(cd63, i63, carry);
    scan3_k<<<32768, 256, 0, stream>>>(a_p, s_p, carry, rec);

    // out_proj + residual -> d_out holds x2
    gemm8p_k<EPI_ADDRES><<<dim3(4, 32), 512, LDSB, stream>>>(rec, wopb, 8192, 1024, 1024,
                                                             out, nullptr, x, 1024);
    // ffn
    rmsnorm_k<<<8192, 256, 0, stream>>>(out, fnw, hn);
    gemm8p_k<EPI_GU><<<dim3(32, 32), 512, LDSB, stream>>>(hn, wgub, 8192, 8192, 1024,
                                                          nullptr, act, nullptr, 4096);
    // down-proj + residual, in place on d_out
    gemm8p_k<EPI_ADDRES><<<dim3(4, 32), 512, LDSB, stream>>>(act, wdnb, 8192, 1024, 4096,
                                                             out, nullptr, out, 1024);
}

// Round 5
// 480.849 us; speedup vs baseline: 1.2313x; 1.1666x over previous
//
#include <hip/hip_runtime.h>

typedef __bf16 bf16_t;
typedef bf16_t bf16x4 __attribute__((ext_vector_type(4)));
typedef bf16_t bf16x8 __attribute__((ext_vector_type(8)));
typedef float f32x4 __attribute__((ext_vector_type(4)));

#define DD 1024
#define TT 4096

__device__ __forceinline__ void gload16(const void* g, void* l) {
    __builtin_amdgcn_global_load_lds(
        (const __attribute__((address_space(1))) void*)g,
        (__attribute__((address_space(3))) void*)l, 16, 0, 0);
}

// ---------------- fp32 -> bf16 convert ----------------
__global__ __launch_bounds__(256) void cvt_bf16_k(const float* __restrict__ s,
                                                  bf16_t* __restrict__ d, int n) {
    int i = (blockIdx.x * 256 + threadIdx.x) * 4;
    if (i < n) {
        const float4 v = *(const float4*)(s + i);
        bf16x4 o;
        o[0] = (bf16_t)v.x; o[1] = (bf16_t)v.y; o[2] = (bf16_t)v.z; o[3] = (bf16_t)v.w;
        *(bf16x4*)(d + i) = o;
    }
}

// ---------------- interleaved convert: dst row 2c = s0 row c, 2c+1 = s1 row c ----------------
__global__ __launch_bounds__(256) void cvt_ileave_k(const float* __restrict__ s0,
                                                    const float* __restrict__ s1,
                                                    bf16_t* __restrict__ d, int total) {
    int i = (blockIdx.x * 256 + threadIdx.x) * 4;
    if (i < total) {
        const int rp = i >> 10, k = i & 1023;
        const int c = rp >> 1;
        const float* src = ((rp & 1) ? s1 : s0) + (long)c * 1024 + k;
        const float4 v = *(const float4*)src;
        bf16x4 o;
        o[0] = (bf16_t)v.x; o[1] = (bf16_t)v.y; o[2] = (bf16_t)v.z; o[3] = (bf16_t)v.w;
        *(bf16x4*)(d + i) = o;
    }
}

// ---------------- rmsnorm (1 block per row, 256 thr x 4 elems), bf16 out ----------------
__global__ __launch_bounds__(256) void rmsnorm_k(const float* __restrict__ x,
                                                 const float* __restrict__ w,
                                                 bf16_t* __restrict__ ob) {
    const long row = blockIdx.x;
    const float* xr = x + row * DD;
    const int t4 = threadIdx.x * 4;
    float4 v = *(const float4*)(xr + t4);
    float s = v.x*v.x + v.y*v.y + v.z*v.z + v.w*v.w;
    #pragma unroll
    for (int off = 1; off < 64; off <<= 1) s += __shfl_xor(s, off);
    __shared__ float red[4];
    if ((threadIdx.x & 63) == 0) red[threadIdx.x >> 6] = s;
    __syncthreads();
    float tot = red[0] + red[1] + red[2] + red[3];
    float sc = rsqrtf(tot * (1.0f / DD) + 1e-6f);
    float4 wv = *(const float4*)(w + t4);
    bf16x4 o;
    o[0] = (bf16_t)(v.x*sc*wv.x); o[1] = (bf16_t)(v.y*sc*wv.y);
    o[2] = (bf16_t)(v.z*sc*wv.z); o[3] = (bf16_t)(v.w*sc*wv.w);
    *(bf16x4*)(ob + row * DD + t4) = o;
}

// ---------------- causal depthwise conv K=4 (bf16 in, bf16 out) ----------------
__global__ __launch_bounds__(256) void conv_k(const bf16_t* __restrict__ h,
                                              const float* __restrict__ cw,
                                              const float* __restrict__ cb,
                                              bf16_t* __restrict__ hc) {
    const long idx = (long)blockIdx.x * 256 + threadIdx.x;  // over B*T*D
    const int d = (int)(idx & (DD - 1));
    const long bt = idx >> 10;
    const int t = (int)(bt & (TT - 1));
    const float w0 = cw[d*4+0], w1 = cw[d*4+1], w2 = cw[d*4+2], w3 = cw[d*4+3];
    const bf16_t* hp = h + bt * DD + d;
    float acc = cb[d] + (float)hp[0] * w3;
    if (t >= 1) acc += (float)hp[-DD]     * w2;
    if (t >= 2) acc += (float)hp[-2*DD]   * w1;
    if (t >= 3) acc += (float)hp[-3*DD]   * w0;
    hc[idx] = (bf16_t)acc;
}

// ---------------- scan pass1: per-chunk summaries only (cd63, i63) ----------------
__global__ __launch_bounds__(256) void scan1_k(const float* __restrict__ ap,
                                               const float* __restrict__ sp,
                                               float* __restrict__ cd63,
                                               float* __restrict__ i63) {
    const int d = blockIdx.x * 256 + threadIdx.x;  // 0..1023
    const int c = blockIdx.y;                      // chunk 0..63
    const int b = blockIdx.z;                      // batch
    const long rowbase = (long)b * TT + (long)c * 64;
    float la = 0.0f, rs = 0.0f, cdv = 0.0f, it = 0.0f;
    for (int t = 0; t < 64; t++) {
        const long off = (rowbase + t) * DD + d;
        const float a = ap[off];
        const float s = sp[off];
        const float sig = sqrtf(fmaxf(1.0f - a * a, 1e-8f)) * s;
        la += __logf(fmaxf(a, 1e-10f));
        cdv = __expf(la);
        rs += sig / fmaxf(cdv, 1e-10f);
        it = cdv * rs;
    }
    const long o = ((long)b * 64 + c) * DD + d;
    cd63[o] = cdv;
    i63[o]  = it;
}

// ---------------- pass2: cross-chunk carry (state ENTERING each chunk) ----------------
__global__ __launch_bounds__(256) void scan2_k(const float* __restrict__ cd63,
                                               const float* __restrict__ i63,
                                               float* __restrict__ carry_in) {
    const int g = blockIdx.x * 256 + threadIdx.x;  // 0..2047
    const int b = g >> 10, d = g & (DD - 1);
    float st = 0.0f;
    for (int c = 0; c < 64; c++) {
        const long o = ((long)b * 64 + c) * DD + d;
        carry_in[o] = st;
        st = i63[o] + cd63[o] * st;
    }
}

// ---------------- pass3: recompute chunk recurrence, fold carry, write bf16 ----------------
__global__ __launch_bounds__(256) void scan3_k(const float* __restrict__ ap,
                                               const float* __restrict__ sp,
                                               const float* __restrict__ carry_in,
                                               bf16_t* __restrict__ rec) {
    const int d = blockIdx.x * 256 + threadIdx.x;
    const int c = blockIdx.y;
    const int b = blockIdx.z;
    const long rowbase = (long)b * TT + (long)c * 64;
    const float carry = carry_in[((long)b * 64 + c) * DD + d];
    float la = 0.0f, rs = 0.0f;
    for (int t = 0; t < 64; t++) {
        const long off = (rowbase + t) * DD + d;
        const float a = ap[off];
        const float s = sp[off];
        const float sig = sqrtf(fmaxf(1.0f - a * a, 1e-8f)) * s;
        la += __logf(fmaxf(a, 1e-10f));
        const float cdv = __expf(la);
        rs += sig / fmaxf(cdv, 1e-10f);
        rec[off] = (bf16_t)(cdv * rs + cdv * carry);
    }
}

// ---------------- bf16 GEMM, C = A(M,K) * B(N,K)^T ----------------
// BM=256, BN=NREP*64, BK=64, 8 waves (2M x 4N), 4-phase schedule.
// T4 counted vmcnt, derived load-slot schedule:
//   tile τ's B loads at iter τ-2 ph2/ph3 (into current read buffer's B region,
//   dead after ph1's Bf[1] reads -> >=1 barrier separation), A loads at iter
//   τ-1 ph0/ph1. vmcnt(2+NREP) at ph0 drains exactly tile t.
// Phase read balance: ph0 = 4B+4A, ph1 = 4A+NREP*... Bf[1], ph2/3 = 4A each.
// T2 swizzle, T5 setprio, T1 XCD chunk w/ column-major order inside chunk.
enum { EPI_SIGB = 0, EPI_ADDRES = 1, EPI_IV = 2, EPI_GU = 3 };

template<int EPI, int NREP>
__global__ __launch_bounds__(512, 2) void gemm8p_k(const bf16_t* __restrict__ Ag,
                                                   const bf16_t* __restrict__ Bg,
                                                   int M, int N, int K,
                                                   float* outF, bf16_t* outB,
                                                   const float* aux, int ldc) {
    constexpr int BN  = NREP * 64;
    constexpr int ASZ = 16384;        // 256 x 64 bf16
    constexpr int BSZ = BN * 64;
    constexpr int BUF = ASZ + BSZ;
    extern __shared__ bf16_t smem[];  // [2][A | B]
    const int tid = threadIdx.x;
    const int l = tid & 63;
    const int w = tid >> 6;
    const int wm = w >> 2, wn = w & 3;

    // XCD-aware mapping: xcd = lin&7 owns a contiguous chunk; column-major inside.
    const int gx = gridDim.x;
    const int gy = gridDim.y;
    const int lin = blockIdx.y * gx + blockIdx.x;
    long row0, col0;
    if ((gy & 7) == 0) {
        const int rpc = gy >> 3;
        const int q = lin >> 3;
        row0 = (long)((lin & 7) * rpc + q % rpc) * 256;
        col0 = (long)(q / rpc) * (long)BN;
    } else {
        row0 = (long)blockIdx.y * 256;
        col0 = (long)blockIdx.x * BN;
    }

    const int srow = l >> 3;
    const int scol = ((l & 7) ^ srow) * 8;   // pre-swizzled source column
    const long aBase = row0 + srow;
    const long bBase = col0 + srow;
    const int R0a = w * 32;                  // A rows staged by this wave
    const int R0b = w * (BN / 8);            // B rows staged by this wave

    const int NT = K >> 6;
    f32x4 acc[8][NREP] = {};

    // prologue: tile0 B+A into buf0; tile1 B into buf1
    #pragma unroll
    for (int i = 0; i < NREP; i++)
        gload16(Bg + (bBase + R0b + i * 8) * (long)K + scol, &smem[ASZ + (R0b + i * 8) * 64]);
    #pragma unroll
    for (int i = 0; i < 4; i++)
        gload16(Ag + (aBase + R0a + i * 8) * (long)K + scol, &smem[(R0a + i * 8) * 64]);
    #pragma unroll
    for (int i = 0; i < NREP; i++)
        gload16(Bg + (bBase + R0b + i * 8) * (long)K + 64 + scol, &smem[BUF + ASZ + (R0b + i * 8) * 64]);

    const int lq = (l >> 4) * 8;
    const int rA = wm * 128 + (l & 15);
    const int rB = wn * (NREP * 16) + (l & 15);

    for (int t = 0; t < NT; t++) {
        const int cb = (t & 1) * BUF;
        const int ob = BUF - cb;
        const long kg1 = (long)(t + 1) * 64 + scol;
        const long kg2 = (long)(t + 2) * 64 + scol;
        bf16x8 Bf[2][NREP], Af[4];

        // ---- phase 0: issue (t+1)A01; vmcnt; barrier; read Bf[0]+A[mh0,kk0]; MFMA
        if (t + 1 < NT) {
            gload16(Ag + (aBase + R0a) * (long)K + kg1, &smem[ob + R0a * 64]);
            gload16(Ag + (aBase + R0a + 8) * (long)K + kg1, &smem[ob + (R0a + 8) * 64]);
        }
        if (t == NT - 1)            { asm volatile("s_waitcnt vmcnt(0)" ::: "memory"); }
        else if constexpr (NREP == 4) { asm volatile("s_waitcnt vmcnt(6)" ::: "memory"); }
        else                        { asm volatile("s_waitcnt vmcnt(4)" ::: "memory"); }
        asm volatile("s_barrier" ::: "memory");
        #pragma unroll
        for (int n = 0; n < NREP; n++) {
            const int r = rB + n * 16;
            Bf[0][n] = *(const bf16x8*)&smem[cb + ASZ + r * 64 + (((lq * 2) ^ ((r & 7) << 4)) >> 1)];
        }
        #pragma unroll
        for (int m = 0; m < 4; m++) {
            const int r = rA + m * 16;
            Af[m] = *(const bf16x8*)&smem[cb + r * 64 + (((lq * 2) ^ ((r & 7) << 4)) >> 1)];
        }
        __builtin_amdgcn_s_setprio(1);
        #pragma unroll
        for (int m = 0; m < 4; m++)
            #pragma unroll
            for (int n = 0; n < NREP; n++)
                acc[m][n] = __builtin_amdgcn_mfma_f32_16x16x32_bf16(Af[m], Bf[0][n], acc[m][n], 0, 0, 0);
        __builtin_amdgcn_s_setprio(0);
        asm volatile("s_barrier" ::: "memory");

        // ---- phase 1: read A[mh1,kk0] + Bf[1]; issue (t+1)A23; barrier; MFMA
        #pragma unroll
        for (int m = 0; m < 4; m++) {
            const int r = rA + 64 + m * 16;
            Af[m] = *(const bf16x8*)&smem[cb + r * 64 + (((lq * 2) ^ ((r & 7) << 4)) >> 1)];
        }
        #pragma unroll
        for (int n = 0; n < NREP; n++) {
            const int r = rB + n * 16;
            Bf[1][n] = *(const bf16x8*)&smem[cb + ASZ + r * 64 + ((((lq * 2) ^ ((r & 7) << 4)) ^ 64) >> 1)];
        }
        if (t + 1 < NT) {
            gload16(Ag + (aBase + R0a + 16) * (long)K + kg1, &smem[ob + (R0a + 16) * 64]);
            gload16(Ag + (aBase + R0a + 24) * (long)K + kg1, &smem[ob + (R0a + 24) * 64]);
        }
        asm volatile("s_barrier" ::: "memory");
        __builtin_amdgcn_s_setprio(1);
        #pragma unroll
        for (int m = 0; m < 4; m++)
            #pragma unroll
            for (int n = 0; n < NREP; n++)
                acc[m + 4][n] = __builtin_amdgcn_mfma_f32_16x16x32_bf16(Af[m], Bf[0][n], acc[m + 4][n], 0, 0, 0);
        __builtin_amdgcn_s_setprio(0);
        asm volatile("s_barrier" ::: "memory");

        // ---- phase 2: read A[mh0,kk1]; issue (t+2)B first half into cb's dead B region; MFMA
        #pragma unroll
        for (int m = 0; m < 4; m++) {
            const int r = rA + m * 16;
            Af[m] = *(const bf16x8*)&smem[cb + r * 64 + ((((lq + 32) * 2) ^ ((r & 7) << 4)) >> 1)];
        }
        if (t + 2 < NT) {
            gload16(Bg + (bBase + R0b) * (long)K + kg2, &smem[cb + ASZ + R0b * 64]);
            if constexpr (NREP == 4)
                gload16(Bg + (bBase + R0b + 8) * (long)K + kg2, &smem[cb + ASZ + (R0b + 8) * 64]);
        }
        asm volatile("s_barrier" ::: "memory");
        __builtin_amdgcn_s_setprio(1);
        #pragma unroll
        for (int m = 0; m < 4; m++)
            #pragma unroll
            for (int n = 0; n < NREP; n++)
                acc[m][n] = __builtin_amdgcn_mfma_f32_16x16x32_bf16(Af[m], Bf[1][n], acc[m][n], 0, 0, 0);
        __builtin_amdgcn_s_setprio(0);
        asm volatile("s_barrier" ::: "memory");

        // ---- phase 3: read A[mh1,kk1]; issue (t+2)B second half; MFMA
        #pragma unroll
        for (int m = 0; m < 4; m++) {
            const int r = rA + 64 + m * 16;
            Af[m] = *(const bf16x8*)&smem[cb + r * 64 + ((((lq + 32) * 2) ^ ((r & 7) << 4)) >> 1)];
        }
        if (t + 2 < NT) {
            if constexpr (NREP == 4) {
                gload16(Bg + (bBase + R0b + 16) * (long)K + kg2, &smem[cb + ASZ + (R0b + 16) * 64]);
                gload16(Bg + (bBase + R0b + 24) * (long)K + kg2, &smem[cb + ASZ + (R0b + 24) * 64]);
            } else {
                gload16(Bg + (bBase + R0b + 8) * (long)K + kg2, &smem[cb + ASZ + (R0b + 8) * 64]);
            }
        }
        asm volatile("s_barrier" ::: "memory");
        __builtin_amdgcn_s_setprio(1);
        #pragma unroll
        for (int m = 0; m < 4; m++)
            #pragma unroll
            for (int n = 0; n < NREP; n++)
                acc[m + 4][n] = __builtin_amdgcn_mfma_f32_16x16x32_bf16(Af[m], Bf[1][n], acc[m + 4][n], 0, 0, 0);
        __builtin_amdgcn_s_setprio(0);
        asm volatile("s_barrier" ::: "memory");
    }

    // ---- epilogue ----
    #pragma unroll
    for (int m = 0; m < 8; m++) {
        const long r0 = row0 + wm * 128 + m * 16 + (l >> 4) * 4;
        #pragma unroll
        for (int n = 0; n < NREP; n++) {
            const long cc = col0 + wn * (NREP * 16) + n * 16 + (l & 15);
            f32x4 v = acc[m][n];
            #pragma unroll
            for (int j = 0; j < 4; j++) {
                const long r = r0 + j;
                const float xv = v[j];
                if (EPI == EPI_SIGB) {
                    outF[r * ldc + cc] = 1.0f / (1.0f + __expf(-(xv + aux[cc])));
                } else if (EPI == EPI_ADDRES) {
                    outF[r * ldc + cc] = xv + aux[r * ldc + cc];
                } else if (EPI == EPI_IV) {
                    const float px = __shfl_xor(xv, 1);
                    if ((l & 1) == 0)
                        outF[r * ldc + (cc >> 1)] = px / (1.0f + __expf(-xv));
                } else {  // EPI_GU
                    const float px = __shfl_xor(xv, 1);
                    if ((l & 1) == 0)
                        outB[r * ldc + (cc >> 1)] = (bf16_t)(xv / (1.0f + __expf(-xv)) * px);
                }
            }
        }
    }
}

extern "C" void kernel_launch(void* const* d_in, const int* in_sizes, int n_in,
                              void* d_out, int out_size, void* d_ws, size_t ws_size,
                              hipStream_t stream) {
    const float* x   = (const float*)d_in[0];
    const float* pnw = (const float*)d_in[1];
    const float* cw  = (const float*)d_in[2];
    const float* cb  = (const float*)d_in[3];
    const float* wa  = (const float*)d_in[4];
    const float* wi  = (const float*)d_in[5];
    const float* wv  = (const float*)d_in[6];
    const float* wop = (const float*)d_in[7];
    const float* db  = (const float*)d_in[8];
    const float* fnw = (const float*)d_in[9];
    const float* wgu = (const float*)d_in[10];
    const float* wdn = (const float*)d_in[11];
    float* out = (float*)d_out;

    // ---- workspace layout (total ~129.5 MiB) ----
    char* ws = (char*)d_ws;
    bf16_t* wab   = (bf16_t*)(ws + 0);            // 1024x1024 bf16
    bf16_t* wivb  = (bf16_t*)(ws + 2097152);      // 2048x1024 bf16 (i|v interleaved)
    bf16_t* wopb  = (bf16_t*)(ws + 6291456);      // 1024x1024 bf16
    bf16_t* wgub  = (bf16_t*)(ws + 8388608);      // 8192x1024 bf16 (gate|up interleaved)
    bf16_t* wdnb  = (bf16_t*)(ws + 25165824);     // 4096x1024 bf16
    bf16_t* hb    = (bf16_t*)(ws + 33554432);     // 8192x1024 bf16 (reused: hn)
    bf16_t* hn    = hb;
    bf16_t* hc    = (bf16_t*)(ws + 50331648);     // 8192x1024 bf16 (reused: rec)
    bf16_t* rec   = hc;
    float*  a_p   = (float*)(ws + 67108864);      // 8192x1024 f32 (reused by act)
    float*  s_p   = (float*)(ws + 100663296);     // 8192x1024 f32
    bf16_t* act   = (bf16_t*)(ws + 67108864);     // 8192x4096 bf16 (after scan)
    float*  cd63  = (float*)(ws + 134217728);
    float*  i63   = (float*)(ws + 134742016);
    float*  carry = (float*)(ws + 135266304);

    const int LDS4 = 131072;   // NREP=4: (16K + 16K) * 2 bufs * 2B
    const int LDS2 = 98304;    // NREP=2: (16K + 8K) * 2 bufs * 2B
    hipFuncSetAttribute((const void*)gemm8p_k<EPI_SIGB, 2>,   hipFuncAttributeMaxDynamicSharedMemorySize, LDS2);
    hipFuncSetAttribute((const void*)gemm8p_k<EPI_IV, 4>,     hipFuncAttributeMaxDynamicSharedMemorySize, LDS4);
    hipFuncSetAttribute((const void*)gemm8p_k<EPI_ADDRES, 2>, hipFuncAttributeMaxDynamicSharedMemorySize, LDS2);
    hipFuncSetAttribute((const void*)gemm8p_k<EPI_GU, 4>,     hipFuncAttributeMaxDynamicSharedMemorySize, LDS4);

    // weight converts / interleaves
    cvt_bf16_k  <<<1024, 256, 0, stream>>>(wa,  wab,  1048576);
    cvt_ileave_k<<<2048, 256, 0, stream>>>(wi,  wv, wivb, 2097152);
    cvt_bf16_k  <<<1024, 256, 0, stream>>>(wop, wopb, 1048576);
    cvt_ileave_k<<<8192, 256, 0, stream>>>(wgu, wgu + 4194304, wgub, 8388608);
    cvt_bf16_k  <<<4096, 256, 0, stream>>>(wdn, wdnb, 4194304);

    // pre-norm + conv
    rmsnorm_k<<<8192, 256, 0, stream>>>(x, pnw, hb);
    conv_k<<<32768, 256, 0, stream>>>(hb, cw, cb, hc);

    // a-plane: sigmoid(h*w_a^T + db);  s-plane: sigmoid(h*w_i^T) * (h*w_v^T)
    gemm8p_k<EPI_SIGB, 2><<<dim3(8, 32), 512, LDS2, stream>>>(hc, wab,  8192, 1024, 1024,
                                                              a_p, nullptr, db, 1024);
    gemm8p_k<EPI_IV, 4>  <<<dim3(8, 32), 512, LDS4, stream>>>(hc, wivb, 8192, 2048, 1024,
                                                              s_p, nullptr, nullptr, 1024);
    // chunked scan (matches reference's clipped formula); pass3 recomputes
    scan1_k<<<dim3(4, 64, 2), 256, 0, stream>>>(a_p, s_p, cd63, i63);
    scan2_k<<<8, 256, 0, stream>>>(cd63, i63, carry);
    scan3_k<<<dim3(4, 64, 2), 256, 0, stream>>>(a_p, s_p, carry, rec);

    // out_proj + residual -> d_out holds x2
    gemm8p_k<EPI_ADDRES, 2><<<dim3(8, 32), 512, LDS2, stream>>>(rec, wopb, 8192, 1024, 1024,
                                                                out, nullptr, x, 1024);
    // ffn
    rmsnorm_k<<<8192, 256, 0, stream>>>(out, fnw, hn);
    gemm8p_k<EPI_GU, 4><<<dim3(32, 32), 512, LDS4, stream>>>(hn, wgub, 8192, 8192, 1024,
                                                             nullptr, act, nullptr, 4096);
    // down-proj + residual, in place on d_out
    gemm8p_k<EPI_ADDRES, 2><<<dim3(8, 32), 512, LDS2, stream>>>(act, wdnb, 8192, 1024, 4096,
                                                                out, nullptr, out, 1024);
}

// Round 6
// 468.812 us; speedup vs baseline: 1.2629x; 1.0257x over previous
//
#include <hip/hip_runtime.h>

typedef __bf16 bf16_t;
typedef bf16_t bf16x4 __attribute__((ext_vector_type(4)));
typedef bf16_t bf16x8 __attribute__((ext_vector_type(8)));
typedef float f32x4 __attribute__((ext_vector_type(4)));

#define DD 1024
#define TT 4096

__device__ __forceinline__ void gload16(const void* g, void* l) {
    __builtin_amdgcn_global_load_lds(
        (const __attribute__((address_space(1))) void*)g,
        (__attribute__((address_space(3))) void*)l, 16, 0, 0);
}

// ---------------- fp32 -> bf16 convert ----------------
__global__ __launch_bounds__(256) void cvt_bf16_k(const float* __restrict__ s,
                                                  bf16_t* __restrict__ d, int n) {
    int i = (blockIdx.x * 256 + threadIdx.x) * 4;
    if (i < n) {
        const float4 v = *(const float4*)(s + i);
        bf16x4 o;
        o[0] = (bf16_t)v.x; o[1] = (bf16_t)v.y; o[2] = (bf16_t)v.z; o[3] = (bf16_t)v.w;
        *(bf16x4*)(d + i) = o;
    }
}

// ---------------- interleaved convert: dst row 2c = s0 row c, 2c+1 = s1 row c ----------------
__global__ __launch_bounds__(256) void cvt_ileave_k(const float* __restrict__ s0,
                                                    const float* __restrict__ s1,
                                                    bf16_t* __restrict__ d, int total) {
    int i = (blockIdx.x * 256 + threadIdx.x) * 4;
    if (i < total) {
        const int rp = i >> 10, k = i & 1023;
        const int c = rp >> 1;
        const float* src = ((rp & 1) ? s1 : s0) + (long)c * 1024 + k;
        const float4 v = *(const float4*)src;
        bf16x4 o;
        o[0] = (bf16_t)v.x; o[1] = (bf16_t)v.y; o[2] = (bf16_t)v.z; o[3] = (bf16_t)v.w;
        *(bf16x4*)(d + i) = o;
    }
}

// ---------------- rmsnorm (1 block per row, 256 thr x 4 elems), bf16 out ----------------
__global__ __launch_bounds__(256) void rmsnorm_k(const float* __restrict__ x,
                                                 const float* __restrict__ w,
                                                 bf16_t* __restrict__ ob) {
    const long row = blockIdx.x;
    const float* xr = x + row * DD;
    const int t4 = threadIdx.x * 4;
    float4 v = *(const float4*)(xr + t4);
    float s = v.x*v.x + v.y*v.y + v.z*v.z + v.w*v.w;
    #pragma unroll
    for (int off = 1; off < 64; off <<= 1) s += __shfl_xor(s, off);
    __shared__ float red[4];
    if ((threadIdx.x & 63) == 0) red[threadIdx.x >> 6] = s;
    __syncthreads();
    float tot = red[0] + red[1] + red[2] + red[3];
    float sc = rsqrtf(tot * (1.0f / DD) + 1e-6f);
    float4 wv = *(const float4*)(w + t4);
    bf16x4 o;
    o[0] = (bf16_t)(v.x*sc*wv.x); o[1] = (bf16_t)(v.y*sc*wv.y);
    o[2] = (bf16_t)(v.z*sc*wv.z); o[3] = (bf16_t)(v.w*sc*wv.w);
    *(bf16x4*)(ob + row * DD + t4) = o;
}

// ---------------- causal depthwise conv K=4 (bf16 in, bf16 out) ----------------
__global__ __launch_bounds__(256) void conv_k(const bf16_t* __restrict__ h,
                                              const float* __restrict__ cw,
                                              const float* __restrict__ cb,
                                              bf16_t* __restrict__ hc) {
    const long idx = (long)blockIdx.x * 256 + threadIdx.x;  // over B*T*D
    const int d = (int)(idx & (DD - 1));
    const long bt = idx >> 10;
    const int t = (int)(bt & (TT - 1));
    const float w0 = cw[d*4+0], w1 = cw[d*4+1], w2 = cw[d*4+2], w3 = cw[d*4+3];
    const bf16_t* hp = h + bt * DD + d;
    float acc = cb[d] + (float)hp[0] * w3;
    if (t >= 1) acc += (float)hp[-DD]     * w2;
    if (t >= 2) acc += (float)hp[-2*DD]   * w1;
    if (t >= 3) acc += (float)hp[-3*DD]   * w0;
    hc[idx] = (bf16_t)acc;
}

// ---------------- scan pass1: per-chunk summaries only (cd63, i63) ----------------
__global__ __launch_bounds__(256) void scan1_k(const float* __restrict__ ap,
                                               const float* __restrict__ sp,
                                               float* __restrict__ cd63,
                                               float* __restrict__ i63) {
    const int d = blockIdx.x * 256 + threadIdx.x;  // 0..1023
    const int c = blockIdx.y;                      // chunk 0..63
    const int b = blockIdx.z;                      // batch
    const long rowbase = (long)b * TT + (long)c * 64;
    float la = 0.0f, rs = 0.0f, cdv = 0.0f, it = 0.0f;
    for (int t = 0; t < 64; t++) {
        const long off = (rowbase + t) * DD + d;
        const float a = ap[off];
        const float s = sp[off];
        const float sig = sqrtf(fmaxf(1.0f - a * a, 1e-8f)) * s;
        la += __logf(fmaxf(a, 1e-10f));
        cdv = __expf(la);
        rs += sig / fmaxf(cdv, 1e-10f);
        it = cdv * rs;
    }
    const long o = ((long)b * 64 + c) * DD + d;
    cd63[o] = cdv;
    i63[o]  = it;
}

// ---------------- pass2: cross-chunk carry (state ENTERING each chunk) ----------------
__global__ __launch_bounds__(256) void scan2_k(const float* __restrict__ cd63,
                                               const float* __restrict__ i63,
                                               float* __restrict__ carry_in) {
    const int g = blockIdx.x * 256 + threadIdx.x;  // 0..2047
    const int b = g >> 10, d = g & (DD - 1);
    float st = 0.0f;
    for (int c = 0; c < 64; c++) {
        const long o = ((long)b * 64 + c) * DD + d;
        carry_in[o] = st;
        st = i63[o] + cd63[o] * st;
    }
}

// ---------------- pass3: recompute chunk recurrence, fold carry, write bf16 ----------------
__global__ __launch_bounds__(256) void scan3_k(const float* __restrict__ ap,
                                               const float* __restrict__ sp,
                                               const float* __restrict__ carry_in,
                                               bf16_t* __restrict__ rec) {
    const int d = blockIdx.x * 256 + threadIdx.x;
    const int c = blockIdx.y;
    const int b = blockIdx.z;
    const long rowbase = (long)b * TT + (long)c * 64;
    const float carry = carry_in[((long)b * 64 + c) * DD + d];
    float la = 0.0f, rs = 0.0f;
    for (int t = 0; t < 64; t++) {
        const long off = (rowbase + t) * DD + d;
        const float a = ap[off];
        const float s = sp[off];
        const float sig = sqrtf(fmaxf(1.0f - a * a, 1e-8f)) * s;
        la += __logf(fmaxf(a, 1e-10f));
        const float cdv = __expf(la);
        rs += sig / fmaxf(cdv, 1e-10f);
        rec[off] = (bf16_t)(cdv * rs + cdv * carry);
    }
}

// ---------------- bf16 GEMM, C = A(M,K) * B(N,K)^T ----------------
// BM=256, BN=NREP*64, BK=64, 8 waves (2M x 4N), 2-phase K-loop with pre-read:
//   P0: 32 MFMA (mh0) on frags pre-read last iter; read mh1 frags; barrier.
//   P1: stage tile t+2 into CURRENT buffer's dead regions; 32 MFMA (mh1);
//       vmcnt(4+NREP) drains exactly tile t+1; barrier; pre-read t+1 frags.
// 2 barriers per K-tile; every ds_read crosses >=1 barrier before use; loads
// get a full iteration of slack. Fragment addresses = 2 per-lane bases +
// compile-time imm offsets (+XOR 32 for the kk1 half).
// T2 swizzle, T5 setprio, T1 XCD chunk w/ column-major order inside chunk.
enum { EPI_SIGB = 0, EPI_ADDRES = 1, EPI_IV = 2, EPI_GU = 3 };

template<int EPI, int NREP>
__global__ __launch_bounds__(512, 2) void gemm2p_k(const bf16_t* __restrict__ Ag,
                                                   const bf16_t* __restrict__ Bg,
                                                   int M, int N, int K,
                                                   float* outF, bf16_t* outB,
                                                   const float* aux, int ldc) {
    constexpr int BN  = NREP * 64;
    constexpr int ASZ = 16384;        // 256 x 64 bf16
    constexpr int BSZ = BN * 64;
    constexpr int BUF = ASZ + BSZ;
    extern __shared__ bf16_t smem[];  // [2][A | B]
    const int tid = threadIdx.x;
    const int l = tid & 63;
    const int w = tid >> 6;
    const int wm = w >> 2, wn = w & 3;

    // XCD-aware mapping: xcd = lin&7 owns a contiguous chunk; column-major inside.
    const int gx = gridDim.x;
    const int gy = gridDim.y;
    const int lin = blockIdx.y * gx + blockIdx.x;
    long row0, col0;
    if ((gy & 7) == 0) {
        const int rpc = gy >> 3;
        const int q = lin >> 3;
        row0 = (long)((lin & 7) * rpc + q % rpc) * 256;
        col0 = (long)(q / rpc) * (long)BN;
    } else {
        row0 = (long)blockIdx.y * 256;
        col0 = (long)blockIdx.x * BN;
    }

    const int srow = l >> 3;
    const int scol = ((l & 7) ^ srow) * 8;   // pre-swizzled source column
    const long aBase = row0 + srow;
    const long bBase = col0 + srow;
    const int R0a = w * 32;                  // A rows staged by this wave
    const int R0b = w * (BN / 8);            // B rows staged by this wave

    const int NT = K >> 6;
    f32x4 acc[8][NREP] = {};

    // fragment element-offset bases within one buffer (swizzle folded in).
    const int lq2 = (l >> 4) * 16;           // byte k-offset of this lane quarter
    const int rA = wm * 128 + (l & 15);
    const int rB = wn * (NREP * 16) + (l & 15);
    const int eA0 = rA * 64 + ((lq2 ^ ((rA & 7) << 4)) >> 1);
    const int eB0 = ASZ + rB * 64 + ((lq2 ^ ((rB & 7) << 4)) >> 1);

    #define STAGE_A(tt, off)                                                          \
        { const long kgk = (long)(tt) * 64 + scol;                                    \
          _Pragma("unroll")                                                           \
          for (int i = 0; i < 4; i++)                                                 \
              gload16(Ag + (aBase + R0a + i * 8) * (long)K + kgk,                     \
                      &smem[(off) + (R0a + i * 8) * 64]); }
    #define STAGE_B(tt, off)                                                          \
        { const long kgk = (long)(tt) * 64 + scol;                                    \
          _Pragma("unroll")                                                           \
          for (int i = 0; i < NREP; i++)                                              \
              gload16(Bg + (bBase + R0b + i * 8) * (long)K + kgk,                     \
                      &smem[(off) + ASZ + (R0b + i * 8) * 64]); }

    // prologue: stage tile0 -> buf0, tile1 -> buf1; drain tile0; pre-read tile0.
    STAGE_A(0, 0); STAGE_B(0, 0);
    STAGE_A(1, BUF); STAGE_B(1, BUF);
    if constexpr (NREP == 4) { asm volatile("s_waitcnt vmcnt(8)" ::: "memory"); }
    else                     { asm volatile("s_waitcnt vmcnt(6)" ::: "memory"); }
    asm volatile("s_barrier" ::: "memory");

    bf16x8 pA[2][4], pB[2][NREP];
    #pragma unroll
    for (int kk = 0; kk < 2; kk++) {
        const int xo = kk * 32;
        #pragma unroll
        for (int n = 0; n < NREP; n++)
            pB[kk][n] = *(const bf16x8*)&smem[(eB0 ^ xo) + n * 1024];
        #pragma unroll
        for (int m = 0; m < 4; m++)
            pA[kk][m] = *(const bf16x8*)&smem[(eA0 ^ xo) + m * 1024];
    }

    for (int t = 0; t < NT; t++) {
        const int co = (t & 1) ? BUF : 0;
        const int oo = BUF - co;
        bf16x8 a1[2][4];

        // ---- P0: MFMA mh0 (pre-read frags); read mh1 frags; barrier
        __builtin_amdgcn_s_setprio(1);
        #pragma unroll
        for (int kk = 0; kk < 2; kk++)
            #pragma unroll
            for (int m = 0; m < 4; m++)
                #pragma unroll
                for (int n = 0; n < NREP; n++)
                    acc[m][n] = __builtin_amdgcn_mfma_f32_16x16x32_bf16(pA[kk][m], pB[kk][n], acc[m][n], 0, 0, 0);
        __builtin_amdgcn_s_setprio(0);
        #pragma unroll
        for (int kk = 0; kk < 2; kk++) {
            const int xo = kk * 32;
            #pragma unroll
            for (int m = 0; m < 4; m++)
                a1[kk][m] = *(const bf16x8*)&smem[co + (eA0 ^ xo) + 4096 + m * 1024];
        }
        asm volatile("s_barrier" ::: "memory");

        // ---- P1: stage t+2 into co's dead regions; MFMA mh1; drain t+1; pre-read
        if (t + 2 < NT) { STAGE_A(t + 2, co); STAGE_B(t + 2, co); }
        __builtin_amdgcn_s_setprio(1);
        #pragma unroll
        for (int kk = 0; kk < 2; kk++)
            #pragma unroll
            for (int m = 0; m < 4; m++)
                #pragma unroll
                for (int n = 0; n < NREP; n++)
                    acc[m + 4][n] = __builtin_amdgcn_mfma_f32_16x16x32_bf16(a1[kk][m], pB[kk][n], acc[m + 4][n], 0, 0, 0);
        __builtin_amdgcn_s_setprio(0);
        if (t + 2 < NT) {
            if constexpr (NREP == 4) { asm volatile("s_waitcnt vmcnt(8)" ::: "memory"); }
            else                     { asm volatile("s_waitcnt vmcnt(6)" ::: "memory"); }
        } else if (t + 1 < NT) {
            asm volatile("s_waitcnt vmcnt(0)" ::: "memory");
        }
        asm volatile("s_barrier" ::: "memory");
        if (t + 1 < NT) {
            #pragma unroll
            for (int kk = 0; kk < 2; kk++) {
                const int xo = kk * 32;
                #pragma unroll
                for (int n = 0; n < NREP; n++)
                    pB[kk][n] = *(const bf16x8*)&smem[oo + (eB0 ^ xo) + n * 1024];
                #pragma unroll
                for (int m = 0; m < 4; m++)
                    pA[kk][m] = *(const bf16x8*)&smem[oo + (eA0 ^ xo) + m * 1024];
            }
        }
    }
    #undef STAGE_A
    #undef STAGE_B

    // ---- epilogue ----
    #pragma unroll
    for (int m = 0; m < 8; m++) {
        const long r0 = row0 + wm * 128 + m * 16 + (l >> 4) * 4;
        #pragma unroll
        for (int n = 0; n < NREP; n++) {
            const long cc = col0 + wn * (NREP * 16) + n * 16 + (l & 15);
            f32x4 v = acc[m][n];
            #pragma unroll
            for (int j = 0; j < 4; j++) {
                const long r = r0 + j;
                const float xv = v[j];
                if (EPI == EPI_SIGB) {
                    outF[r * ldc + cc] = 1.0f / (1.0f + __expf(-(xv + aux[cc])));
                } else if (EPI == EPI_ADDRES) {
                    outF[r * ldc + cc] = xv + aux[r * ldc + cc];
                } else if (EPI == EPI_IV) {
                    const float px = __shfl_xor(xv, 1);
                    if ((l & 1) == 0)
                        outF[r * ldc + (cc >> 1)] = px / (1.0f + __expf(-xv));
                } else {  // EPI_GU
                    const float px = __shfl_xor(xv, 1);
                    if ((l & 1) == 0)
                        outB[r * ldc + (cc >> 1)] = (bf16_t)(xv / (1.0f + __expf(-xv)) * px);
                }
            }
        }
    }
}

extern "C" void kernel_launch(void* const* d_in, const int* in_sizes, int n_in,
                              void* d_out, int out_size, void* d_ws, size_t ws_size,
                              hipStream_t stream) {
    const float* x   = (const float*)d_in[0];
    const float* pnw = (const float*)d_in[1];
    const float* cw  = (const float*)d_in[2];
    const float* cb  = (const float*)d_in[3];
    const float* wa  = (const float*)d_in[4];
    const float* wi  = (const float*)d_in[5];
    const float* wv  = (const float*)d_in[6];
    const float* wop = (const float*)d_in[7];
    const float* db  = (const float*)d_in[8];
    const float* fnw = (const float*)d_in[9];
    const float* wgu = (const float*)d_in[10];
    const float* wdn = (const float*)d_in[11];
    float* out = (float*)d_out;

    // ---- workspace layout (total ~129.5 MiB) ----
    char* ws = (char*)d_ws;
    bf16_t* wab   = (bf16_t*)(ws + 0);            // 1024x1024 bf16
    bf16_t* wivb  = (bf16_t*)(ws + 2097152);      // 2048x1024 bf16 (i|v interleaved)
    bf16_t* wopb  = (bf16_t*)(ws + 6291456);      // 1024x1024 bf16
    bf16_t* wgub  = (bf16_t*)(ws + 8388608);      // 8192x1024 bf16 (gate|up interleaved)
    bf16_t* wdnb  = (bf16_t*)(ws + 25165824);     // 4096x1024 bf16
    bf16_t* hb    = (bf16_t*)(ws + 33554432);     // 8192x1024 bf16 (reused: hn)
    bf16_t* hn    = hb;
    bf16_t* hc    = (bf16_t*)(ws + 50331648);     // 8192x1024 bf16 (reused: rec)
    bf16_t* rec   = hc;
    float*  a_p   = (float*)(ws + 67108864);      // 8192x1024 f32 (reused by act)
    float*  s_p   = (float*)(ws + 100663296);     // 8192x1024 f32
    bf16_t* act   = (bf16_t*)(ws + 67108864);     // 8192x4096 bf16 (after scan)
    float*  cd63  = (float*)(ws + 134217728);
    float*  i63   = (float*)(ws + 134742016);
    float*  carry = (float*)(ws + 135266304);

    const int LDS4 = 131072;   // NREP=4
    const int LDS2 = 98304;    // NREP=2
    hipFuncSetAttribute((const void*)gemm2p_k<EPI_SIGB, 2>,   hipFuncAttributeMaxDynamicSharedMemorySize, LDS2);
    hipFuncSetAttribute((const void*)gemm2p_k<EPI_IV, 4>,     hipFuncAttributeMaxDynamicSharedMemorySize, LDS4);
    hipFuncSetAttribute((const void*)gemm2p_k<EPI_ADDRES, 2>, hipFuncAttributeMaxDynamicSharedMemorySize, LDS2);
    hipFuncSetAttribute((const void*)gemm2p_k<EPI_GU, 4>,     hipFuncAttributeMaxDynamicSharedMemorySize, LDS4);

    // weight converts / interleaves
    cvt_bf16_k  <<<1024, 256, 0, stream>>>(wa,  wab,  1048576);
    cvt_ileave_k<<<2048, 256, 0, stream>>>(wi,  wv, wivb, 2097152);
    cvt_bf16_k  <<<1024, 256, 0, stream>>>(wop, wopb, 1048576);
    cvt_ileave_k<<<8192, 256, 0, stream>>>(wgu, wgu + 4194304, wgub, 8388608);
    cvt_bf16_k  <<<4096, 256, 0, stream>>>(wdn, wdnb, 4194304);

    // pre-norm + conv
    rmsnorm_k<<<8192, 256, 0, stream>>>(x, pnw, hb);
    conv_k<<<32768, 256, 0, stream>>>(hb, cw, cb, hc);

    // a-plane: sigmoid(h*w_a^T + db);  s-plane: sigmoid(h*w_i^T) * (h*w_v^T)
    gemm2p_k<EPI_SIGB, 2><<<dim3(8, 32), 512, LDS2, stream>>>(hc, wab,  8192, 1024, 1024,
                                                              a_p, nullptr, db, 1024);
    gemm2p_k<EPI_IV, 4>  <<<dim3(8, 32), 512, LDS4, stream>>>(hc, wivb, 8192, 2048, 1024,
                                                              s_p, nullptr, nullptr, 1024);
    // chunked scan (matches reference's clipped formula); pass3 recomputes
    scan1_k<<<dim3(4, 64, 2), 256, 0, stream>>>(a_p, s_p, cd63, i63);
    scan2_k<<<8, 256, 0, stream>>>(cd63, i63, carry);
    scan3_k<<<dim3(4, 64, 2), 256, 0, stream>>>(a_p, s_p, carry, rec);

    // out_proj + residual -> d_out holds x2
    gemm2p_k<EPI_ADDRES, 2><<<dim3(8, 32), 512, LDS2, stream>>>(rec, wopb, 8192, 1024, 1024,
                                                                out, nullptr, x, 1024);
    // ffn
    rmsnorm_k<<<8192, 256, 0, stream>>>(out, fnw, hn);
    gemm2p_k<EPI_GU, 4><<<dim3(32, 32), 512, LDS4, stream>>>(hn, wgub, 8192, 8192, 1024,
                                                             nullptr, act, nullptr, 4096);
    // down-proj + residual, in place on d_out
    gemm2p_k<EPI_ADDRES, 2><<<dim3(8, 32), 512, LDS2, stream>>>(act, wdnb, 8192, 1024, 4096,
                                                                out, nullptr, out, 1024);
}